// Round 3
// baseline (1909.607 us; speedup 1.0000x reference)
//
#include <hip/hip_runtime.h>
#include <math.h>

#define FS_   44100.0
#define B_    8
#define T_    22050
#define NCH   31
#define LG    2048
#define LH    512
#define MM    12
#define BN    248          // B_*NCH

#define H1LEN 1023         // LH+LH-1

#define C2T   512          // t-tile for ihc
#define C2THR 128          // threads
#define C2T8  1024         // t-tile for conv2 (8 outputs/thread)

#define IHCK  128          // IHC FIR taps

#define MODL  441
#define MODC  50           // MODL*MODC == T_

#define NBLK  62           // k_scan blocks: 4 seqs per wave
#define TQ    5520         // env time-quads per seq (22080/4, padded)
#define ADP   22052        // ad row pitch (multiple of 4 floats -> 16B rows)

// ---- workspace layout (in floats) ----
#define OFF_H1    0                       // 1024
#define OFF_G5    1024                    // 256
#define OFF_X1    1280                    // 176400 (pad to 177696)
#define OFF_HW    177696                  // hw: BN*T_ = 5468400 ; ad alias: BN*ADP = 5468896
#define OFF_AD    OFF_HW
#define OFF_ENV   (OFF_HW + 5468896)      // 5646592 ; env interleaved: NBLK*TQ*16 = 5475840
#define OFF_SEND  (OFF_ENV + 5475840)     // 11122432 ; 297600
#define OFF_SINIT (OFF_SEND + 297600)     // 11420032 ; 297600 ; total 11717632 fl = 46.9 MB

struct ScanP {
  float a1[5], b0[5], factor[5], efl2[5], offset[5], init[5], rinit[5];
  float minlvl, corr, scale;
};
struct ModP {
  float pre[12], pim[12], pb0[12], pLre[12], pLim[12];
  float att;
};

typedef float f32x4_t __attribute__((ext_vector_type(4)));

// ---------- combined hp*me FIR (length 1023) ----------
__global__ void k_h1(const float* __restrict__ hp, const float* __restrict__ me,
                     float* __restrict__ h1) {
  int k = blockIdx.x * blockDim.x + threadIdx.x;
  if (k >= H1LEN) return;
  int j0 = max(0, k - (LH - 1));
  int j1 = min(LH - 1, k);
  float acc = 0.f;
  for (int j = j0; j <= j1; ++j) acc += hp[j] * me[k - j];
  h1[k] = acc;
}

// ---------- IHC LP^5 impulse response: (1-a)^5 * C(k+4,4) * a^k ----------
__global__ void k_g5(float l2a, float c5, float* __restrict__ g5) {
  int k = threadIdx.x;  // 128
  float kf = (float)k;
  float binom = (kf + 1.f) * (kf + 2.f) * (kf + 3.f) * (kf + 4.f) * (1.0f / 24.0f);
  g5[k] = c5 * binom * exp2f(kf * l2a);
}

// ---------- conv1: x (*) h1 -> x1,  K=1023, 1 output/thread ----------
__global__ void k_conv1(const float* __restrict__ x, const float* __restrict__ h1,
                        float* __restrict__ x1) {
  __shared__ float xs[256 + 1022];  // 1278
  __shared__ float hs[H1LEN];
  int b = blockIdx.y;
  int t0 = blockIdx.x * 256;
  const float* xb = x + b * T_;
  for (int i = threadIdx.x; i < 1278; i += 256) {
    int g = t0 - 1022 + i;
    xs[i] = (g >= 0 && g < T_) ? xb[g] : 0.f;
  }
  for (int i = threadIdx.x; i < H1LEN; i += 256) hs[i] = h1[i];
  __syncthreads();
  int t = t0 + threadIdx.x;
  if (t >= T_) return;
  float acc = 0.f;
  for (int k = 0; k < H1LEN; ++k) acc = fmaf(hs[k], xs[threadIdx.x + 1022 - k], acc);
  x1[b * T_ + t] = acc;
}

// ---------- conv2: x1 (*) gt[n] -> hw = relu(y), K=2048, 8 outputs/thread ----------
// 8 outs/thread + 3-float4 sliding window: LDS traffic 1 B/MAC (was 2), half the
// blocks. Lanes read b128 at 32B stride = 2-way bank aliasing (free, m136).
__global__ __launch_bounds__(C2THR) void k_conv2(const float* __restrict__ x1,
                                                 const float* __restrict__ gt,
                                                 float* __restrict__ hw) {
  const int H = LG - 1;  // 2047
  __shared__ __align__(16) float xs[C2T8 + LG];  // 3072
  __shared__ __align__(16) float hs[LG];
  int n = blockIdx.y % NCH, b = blockIdx.y / NCH;
  int t0 = blockIdx.x * C2T8;
  const float* xb = x1 + b * T_;
  for (int i = threadIdx.x; i < C2T8 + LG; i += C2THR) {
    int g = t0 - H + i;
    xs[i] = (g >= 0 && g < T_) ? xb[g] : 0.f;
  }
  for (int i = threadIdx.x; i < LG; i += C2THR) hs[i] = gt[n * LG + i];
  __syncthreads();
  int base = threadIdx.x * 8;
  float a0 = 0.f, a1 = 0.f, a2 = 0.f, a3 = 0.f, a4 = 0.f, a5 = 0.f, a6 = 0.f, a7 = 0.f;
  // window: A = xs[base+H-3-k .. base+H-k], Bv = +4, Cv = +8 (rel index j-c in [-3,7])
  float4 Bv = *(const float4*)&xs[base + H + 1];
  float4 Cv = *(const float4*)&xs[base + H + 5];
  for (int k4 = 0; k4 < LG / 4; ++k4) {
    int k = k4 * 4;
    float4 A  = *(const float4*)&xs[base + H - 3 - k];
    float4 hh = *(const float4*)&hs[k];
    // tap c=0: rel 0..7
    a0 = fmaf(hh.x, A.w,  a0); a1 = fmaf(hh.x, Bv.x, a1); a2 = fmaf(hh.x, Bv.y, a2); a3 = fmaf(hh.x, Bv.z, a3);
    a4 = fmaf(hh.x, Bv.w, a4); a5 = fmaf(hh.x, Cv.x, a5); a6 = fmaf(hh.x, Cv.y, a6); a7 = fmaf(hh.x, Cv.z, a7);
    // tap c=1: rel -1..6
    a0 = fmaf(hh.y, A.z,  a0); a1 = fmaf(hh.y, A.w,  a1); a2 = fmaf(hh.y, Bv.x, a2); a3 = fmaf(hh.y, Bv.y, a3);
    a4 = fmaf(hh.y, Bv.z, a4); a5 = fmaf(hh.y, Bv.w, a5); a6 = fmaf(hh.y, Cv.x, a6); a7 = fmaf(hh.y, Cv.y, a7);
    // tap c=2: rel -2..5
    a0 = fmaf(hh.z, A.y,  a0); a1 = fmaf(hh.z, A.z,  a1); a2 = fmaf(hh.z, A.w,  a2); a3 = fmaf(hh.z, Bv.x, a3);
    a4 = fmaf(hh.z, Bv.y, a4); a5 = fmaf(hh.z, Bv.z, a5); a6 = fmaf(hh.z, Bv.w, a6); a7 = fmaf(hh.z, Cv.x, a7);
    // tap c=3: rel -3..4
    a0 = fmaf(hh.w, A.x,  a0); a1 = fmaf(hh.w, A.y,  a1); a2 = fmaf(hh.w, A.z,  a2); a3 = fmaf(hh.w, A.w,  a3);
    a4 = fmaf(hh.w, Bv.x, a4); a5 = fmaf(hh.w, Bv.y, a5); a6 = fmaf(hh.w, Bv.z, a6); a7 = fmaf(hh.w, Bv.w, a7);
    Cv = Bv; Bv = A;
  }
  float* o = hw + (size_t)(b * NCH + n) * T_;
  int t = t0 + base;
  if (t + 7 < T_) {  // rows are 8B-aligned (T_ even), not 16B -> float2 stores
    *(float2*)(o + t + 0) = make_float2(fmaxf(a0, 0.f), fmaxf(a1, 0.f));
    *(float2*)(o + t + 2) = make_float2(fmaxf(a2, 0.f), fmaxf(a3, 0.f));
    *(float2*)(o + t + 4) = make_float2(fmaxf(a4, 0.f), fmaxf(a5, 0.f));
    *(float2*)(o + t + 6) = make_float2(fmaxf(a6, 0.f), fmaxf(a7, 0.f));
  } else {
    if (t + 0 < T_) o[t + 0] = fmaxf(a0, 0.f);
    if (t + 1 < T_) o[t + 1] = fmaxf(a1, 0.f);
    if (t + 2 < T_) o[t + 2] = fmaxf(a2, 0.f);
    if (t + 3 < T_) o[t + 3] = fmaxf(a3, 0.f);
    if (t + 4 < T_) o[t + 4] = fmaxf(a4, 0.f);
    if (t + 5 < T_) o[t + 5] = fmaxf(a5, 0.f);
    if (t + 6 < T_) o[t + 6] = fmaxf(a6, 0.f);
    if (t + 7 < T_) o[t + 7] = fmaxf(a7, 0.f);
  }
}

// ---------- IHC FIR: hw (*) g5 -> env (interleaved), K=128, 4 outputs/thread ----------
// env layout: [blk=bn/4][tq=t/4][s=bn%4][tt=t%4]  (one float4 store per thread)
__global__ __launch_bounds__(C2THR) void k_ihc(const float* __restrict__ hw,
                                               const float* __restrict__ g5,
                                               float* __restrict__ env) {
  const int H = IHCK - 1;  // 127
  __shared__ __align__(16) float xs[C2T + IHCK];  // 640
  __shared__ __align__(16) float hs[IHCK];
  int bn = blockIdx.y;
  int t0 = blockIdx.x * C2T;
  const float* xb = hw + (size_t)bn * T_;
  for (int i = threadIdx.x; i < C2T + IHCK; i += C2THR) {
    int g = t0 - H + i;
    xs[i] = (g >= 0 && g < T_) ? xb[g] : 0.f;
  }
  if (threadIdx.x < IHCK) hs[threadIdx.x] = g5[threadIdx.x];
  __syncthreads();
  int base = threadIdx.x * 4;
  float a0 = 0.f, a1 = 0.f, a2 = 0.f, a3 = 0.f;
  float4 hi = *(const float4*)&xs[base + H + 1];
  for (int k4 = 0; k4 < IHCK / 4; ++k4) {
    int k = k4 * 4;
    float4 lo = *(const float4*)&xs[base + H - 3 - k];
    float4 hh = *(const float4*)&hs[k];
    a0 = fmaf(hh.x, lo.w, a0); a1 = fmaf(hh.x, hi.x, a1); a2 = fmaf(hh.x, hi.y, a2); a3 = fmaf(hh.x, hi.z, a3);
    a0 = fmaf(hh.y, lo.z, a0); a1 = fmaf(hh.y, lo.w, a1); a2 = fmaf(hh.y, hi.x, a2); a3 = fmaf(hh.y, hi.y, a3);
    a0 = fmaf(hh.z, lo.y, a0); a1 = fmaf(hh.z, lo.z, a1); a2 = fmaf(hh.z, lo.w, a2); a3 = fmaf(hh.z, hi.x, a3);
    a0 = fmaf(hh.w, lo.x, a0); a1 = fmaf(hh.w, lo.y, a1); a2 = fmaf(hh.w, lo.z, a2); a3 = fmaf(hh.w, lo.w, a3);
    hi = lo;
  }
  int t = t0 + base;
  if (t < T_) {  // last quad may carry 2 junk lanes (t=22050/22051) -> never affect stored outputs
    int blk = bn >> 2, s = bn & 3, tq = t >> 2;
    float4* o4 = (float4*)(env + ((size_t)(blk * TQ + tq) * 4 + s) * 4);
    *o4 = make_float4(a0, a1, a2, a3);
  }
}

// ---------- adaptation loops: systolic 5-lane pipeline, 1 seq per 16-lane row ----------
// Lane q (=lane&15) = stage j for q<5; q>=5 idle. Stage j at group k processes t=k-j.
// tmp passes j-1 -> j via DPP row_shr:1; lane q=0 (stage 0) gets `old` = env value
// (bound_ctrl=false) -- no select on the recurrence chain.
//
// Memory pipeline: opaque inline-asm global_load_dwordx4 into an 8-deep
// statically-named register queue (the compiler collapses C-level prefetch),
// counted s_waitcnt (never 0 in the loop). Store batching: outputs are stored
// 8-at-a-time every other substep -> half the saveexec regions.
// vmcnt accounting (steady state, FIFO = loads+stores):
//   A-substep consumes a load with 7 loads + 8 stores issued after it -> vmcnt(15)
//   B-substep consumes a load with 7 loads + 6 stores issued after it -> vmcnt(13)
#define GLD0(DST, PTR)  asm volatile("global_load_dwordx4 %0, %1, off"            : "=v"(DST) : "v"(PTR) : "memory")
#define GLD(DST, PTR, OFFB) \
  asm volatile("global_load_dwordx4 %0, %1, off offset:" #OFFB : "=v"(DST) : "v"(PTR) : "memory")
#define VMWAIT(N) do { asm volatile("s_waitcnt vmcnt(" #N ")" ::: "memory"); \
                       __builtin_amdgcn_sched_barrier(0); } while (0)

__global__ __launch_bounds__(64, 1) void k_scan(const float* __restrict__ env,
                                                float* __restrict__ ad, ScanP p) {
  const int lane = threadIdx.x;
  const int row = lane >> 4, q = lane & 15;
  const int seq = blockIdx.x * 4 + row;
  const bool is4 = (q == 4);
  const float* eb = env + (size_t)blockIdx.x * TQ * 16 + row * 4;  // +tq*16 per quad
  float* o = ad + (size_t)seq * ADP;

#define SEL5(A) (q==0 ? (A)[0] : q==1 ? (A)[1] : q==2 ? (A)[2] : q==3 ? (A)[3] : (A)[4])
  const float A1  = SEL5(p.a1),   B0  = SEL5(p.b0), FAC = SEL5(p.factor);
  const float EF  = SEL5(p.efl2), NEF = -EF,        NOFF = -SEL5(p.offset);
  float st = SEL5(p.init);
  float r  = SEL5(p.rinit);
#undef SEL5
  const float SC = p.scale, NCS = -p.corr * p.scale, ML = p.minlvl;

  float a1st = A1 * st;   // off-critical-path precompute of a1*st for the state fma
  float tmp = 0.f;
  float o0 = 0.f, o1 = 0.f, o2 = 0.f, o3 = 0.f, o4 = 0.f, o5 = 0.f, o6 = 0.f, o7 = 0.f;

  // tmp = min(v, lim) is exact away from v==1 (lim crosses v only there).
  // exarg = fmaf(EF*tin, r, NEF): EF*tin hangs off the DPP path (slack);
  // the recurrence chain sees only one fma between r and exp2.
#define BODY(EV)                                                              \
    float evc = fmaxf((EV), ML);                                              \
    float tin = __int_as_float(__builtin_amdgcn_update_dpp(                   \
        __float_as_int(evc), __float_as_int(tmp), 0x111, 0xF, 0xF, false));   \
    float eft = EF * tin;                                                     \
    float v   = tin * r;                                                      \
    float ex  = __builtin_amdgcn_exp2f(fmaf(eft, r, NEF));                    \
    float lim = fmaf(FAC, __builtin_amdgcn_rcpf(1.0f + ex), NOFF);            \
    tmp = fminf(v, lim);

#define STEP_FILL(EV, K)                                                      \
  { BODY(EV)                                                                  \
    float nst = fmaf(B0, tmp, a1st);                                          \
    st = ((K) >= q) ? nst : st;                                               \
    a1st = A1 * st;                                                           \
    r  = __builtin_amdgcn_rcpf(st); }

#define STEP(EV, OSLOT)                                                       \
  { BODY(EV)                                                                  \
    st = fmaf(B0, tmp, a1st);                                                 \
    a1st = A1 * st;                                                           \
    r  = __builtin_amdgcn_rcpf(st);                                           \
    OSLOT = fmaf(tmp, SC, NCS); }

  // 8-deep opaque prefetch queue + fill quad
  f32x4_t bF, b0, b1, b2, b3, b4, b5, b6, b7;
  GLD0(bF, eb);
  GLD(b0, eb, 64);   GLD(b1, eb, 128);  GLD(b2, eb, 192);  GLD(b3, eb, 256);
  GLD(b4, eb, 320);  GLD(b5, eb, 384);  GLD(b6, eb, 448);  GLD(b7, eb, 512);
  VMWAIT(0);

  // pipeline fill: groups 0..3 (stage-4 t < 0, no stores), quad 0
  STEP_FILL(bF.x, 0) STEP_FILL(bF.y, 1) STEP_FILL(bF.z, 2) STEP_FILL(bF.w, 3)

  const float* pld = eb + 9 * 16;  // next quad to load (quad 9)
  float* po = o;                   // next store base (t = 32*j)

#define SUBSTEP_A(BUF, BOFF)                                                  \
    VMWAIT(15);                                                               \
    STEP(BUF.x, o0) STEP(BUF.y, o1) STEP(BUF.z, o2) STEP(BUF.w, o3)           \
    GLD(BUF, pld, BOFF);

#define SUBSTEP_B(BUF, FOFF, BOFF)                                            \
    VMWAIT(13);                                                               \
    STEP(BUF.x, o4) STEP(BUF.y, o5) STEP(BUF.z, o6) STEP(BUF.w, o7)           \
    if (is4) { *(float4*)(po + (FOFF))     = make_float4(o0, o1, o2, o3);     \
               *(float4*)(po + (FOFF) + 4) = make_float4(o4, o5, o6, o7); }   \
    GLD(BUF, pld, BOFF);

  // main: 689 iterations x 8 quads = quads 1..5512, groups 4..22051 -> t=0..22047.
  // Refills run to quad 5520 (past this row's TQ region -> next block's region /
  // OFF_SEND scratch: allocated, dead data).
  for (int j = 0; j < 689; ++j) {
    SUBSTEP_A(b0, 0)
    SUBSTEP_B(b1, 0, 64)
    SUBSTEP_A(b2, 128)
    SUBSTEP_B(b3, 8, 192)
    SUBSTEP_A(b4, 256)
    SUBSTEP_B(b5, 16, 320)
    SUBSTEP_A(b6, 384)
    SUBSTEP_B(b7, 24, 448)
    pld += 8 * 16;
    po  += 32;
  }
#undef SUBSTEP_A
#undef SUBSTEP_B

  // drain: groups 22052, 22053 -> t = 22048, 22049 (+2 pad floats, row pitch 22052)
  STEP(0.f, o0) STEP(0.f, o1)
  if (is4) *(float4*)(o + 22048) = make_float4(o0, o1, o2, o3);
#undef STEP
#undef STEP_FILL
#undef BODY
}

// ---------- modulation filterbank, chunk-parallel linear scan ----------
__global__ void k_modA(const float* __restrict__ ad, float2* __restrict__ send, ModP mp) {
  int id = blockIdx.x * 256 + threadIdx.x;
  if (id >= MODC * BN * MM) return;
  int m = id % MM, bn = (id / MM) % BN, c = id / (MM * BN);
  const float* a = ad + (size_t)bn * ADP + c * MODL;
  float pre = mp.pre[m], pim = mp.pim[m], b0 = mp.pb0[m];
  float sre = 0.f, sim = 0.f;
#pragma unroll 4
  for (int i = 0; i < MODL; ++i) {
    float xv = a[i];
    float nre = fmaf(pre, sre, fmaf(-pim, sim, b0 * xv));
    sim = fmaf(pre, sim, pim * sre);
    sre = nre;
  }
  send[id] = make_float2(sre, sim);
}

__global__ void k_modB(const float2* __restrict__ send, float2* __restrict__ sinit, ModP mp) {
  int id = blockIdx.x * blockDim.x + threadIdx.x;
  if (id >= BN * MM) return;
  int m = id % MM;
  float pLre = mp.pLre[m], pLim = mp.pLim[m];
  float Sre = 0.f, Sim = 0.f;
  for (int c = 0; c < MODC; ++c) {
    int idx = c * BN * MM + id;
    sinit[idx] = make_float2(Sre, Sim);
    float2 se = send[idx];
    float nre = pLre * Sre - pLim * Sim + se.x;
    Sim = pLre * Sim + pLim * Sre + se.y;
    Sre = nre;
  }
}

__global__ void k_modC(const float* __restrict__ ad, const float2* __restrict__ sinit,
                       float* __restrict__ out, ModP mp) {
  int id = blockIdx.x * 256 + threadIdx.x;
  if (id >= MODC * BN * MM) return;
  int m = id % MM, bn = (id / MM) % BN, c = id / (MM * BN);
  const float* a = ad + (size_t)bn * ADP + c * MODL;
  float* o = out + ((size_t)bn * MM + m) * T_ + c * MODL;
  float2 s0 = sinit[id];
  float sre = s0.x, sim = s0.y;
  float pre = mp.pre[m], pim = mp.pim[m], b0 = mp.pb0[m], att = mp.att;
  bool low = (m < 3);  // mfc <= 10 Hz
#pragma unroll 4
  for (int i = 0; i < MODL; ++i) {
    float xv = a[i];
    float nre = fmaf(pre, sre, fmaf(-pim, sim, b0 * xv));
    sim = fmaf(pre, sim, pim * sre);
    sre = nre;
    float mag = att * sqrtf(fmaf(sre, sre, fmaf(sim, sim, 1e-12f)));
    o[i] = low ? sre : mag;
  }
}

extern "C" void kernel_launch(void* const* d_in, const int* in_sizes, int n_in,
                              void* d_out, int out_size, void* d_ws, size_t ws_size,
                              hipStream_t stream) {
  const float* x  = (const float*)d_in[0];
  const float* hp = (const float*)d_in[1];
  const float* me = (const float*)d_in[2];
  const float* gt = (const float*)d_in[3];
  float* ws  = (float*)d_ws;
  float* out = (float*)d_out;

  // ---- host-side constant computation (double precision) ----
  ScanP sp;
  const double taus[5] = {0.005, 0.05, 0.129, 0.253, 0.5};
  for (int j = 0; j < 5; ++j) {
    double a1 = exp(-1.0 / (FS_ * taus[j]));
    double init = pow(1e-5, pow(2.0, -(double)(j + 1)));
    double maxv = (1.0 - init * init) * 5.0 - 1.0;
    sp.a1[j] = (float)a1;
    sp.b0[j] = (float)(1.0 - a1);
    sp.factor[j] = (float)(2.0 * maxv);
    sp.efl2[j] = (float)(-2.0 / maxv * 1.4426950408889634);  // expfac * log2(e)
    sp.offset[j] = (float)(maxv - 1.0);
    sp.init[j] = (float)init;
    sp.rinit[j] = (float)(1.0 / init);
  }
  sp.minlvl = 1e-5f;
  double corr = pow(1e-5, pow(2.0, -5.0));
  sp.corr = (float)corr;
  sp.scale = (float)(100.0 / (1.0 - corr));

  ModP mp;
  const double mfc[12] = {2.5, 5.0, 10.0, 16.7, 27.8, 46.3, 77.2, 128.6, 214.3, 357.2, 595.4, 992.3};
  for (int m = 0; m < 12; ++m) {
    double r = exp(-M_PI * (mfc[m] / 2.0) / FS_);
    double th = 2.0 * M_PI * mfc[m] / FS_;
    mp.pre[m] = (float)(r * cos(th));
    mp.pim[m] = (float)(r * sin(th));
    mp.pb0[m] = (float)(1.0 - r);
    double rL = pow(r, (double)MODL);
    mp.pLre[m] = (float)(rL * cos((double)MODL * th));
    mp.pLim[m] = (float)(rL * sin((double)MODL * th));
  }
  mp.att = (float)(1.0 / sqrt(2.0));

  double alp = exp(-2.0 * M_PI * 2000.0 / FS_);
  float l2a = (float)(log(alp) * 1.4426950408889634);
  float c5  = (float)pow(1.0 - alp, 5.0);

  float* h1  = ws + OFF_H1;
  float* g5  = ws + OFF_G5;
  float* x1  = ws + OFF_X1;
  float* hw  = ws + OFF_HW;
  float* env = ws + OFF_ENV;
  float* ad  = ws + OFF_AD;  // aliases hw (dead after IHC)
  float2* send  = (float2*)(ws + OFF_SEND);
  float2* sinit = (float2*)(ws + OFF_SINIT);

  k_h1<<<dim3(2), dim3(512), 0, stream>>>(hp, me, h1);
  k_g5<<<dim3(1), dim3(128), 0, stream>>>(l2a, c5, g5);
  k_conv1<<<dim3(87, B_), dim3(256), 0, stream>>>(x, h1, x1);
  k_conv2<<<dim3((T_ + C2T8 - 1) / C2T8, BN), dim3(C2THR), 0, stream>>>(x1, gt, hw);
  k_ihc<<<dim3((T_ + C2T - 1) / C2T, BN), dim3(C2THR), 0, stream>>>(hw, g5, env);
  k_scan<<<dim3(NBLK), dim3(64), 0, stream>>>(env, ad, sp);  // 4 seqs/wave, 5-lane systolic
  int nmod = MODC * BN * MM;
  k_modA<<<dim3((nmod + 255) / 256), dim3(256), 0, stream>>>(ad, send, mp);
  k_modB<<<dim3((BN * MM + 255) / 256), dim3(256), 0, stream>>>(send, sinit, mp);
  k_modC<<<dim3((nmod + 255) / 256), dim3(256), 0, stream>>>(ad, sinit, out, mp);
}

// Round 5
// 1765.746 us; speedup vs baseline: 1.0815x; 1.0815x over previous
//
#include <hip/hip_runtime.h>
#include <math.h>

#define FS_   44100.0
#define B_    8
#define T_    22050
#define NCH   31
#define LG    2048
#define LH    512
#define MM    12
#define BN    248          // B_*NCH

#define H1LEN 1023         // LH+LH-1

#define C2T   512          // t-tile for conv2/ihc
#define C2THR 128          // threads (each does 4 consecutive t)

#define IHCK  128          // IHC FIR taps

#define MODL  441
#define MODC  50           // MODL*MODC == T_

#define NBLK  62           // k_scan blocks: 4 seqs per wave
#define TQ    5520         // env time-quads per seq (22080/4, padded)
#define ADP   22052        // ad row pitch (multiple of 4 floats -> 16B rows)

// ---- workspace layout (in floats) ----
#define OFF_H1    0                       // 1024
#define OFF_G5    1024                    // 256
#define OFF_X1    1280                    // 176400 (pad to 177696)
#define OFF_HW    177696                  // hw: BN*T_ = 5468400 ; ad alias: BN*ADP = 5468896
#define OFF_AD    OFF_HW
#define OFF_ENV   (OFF_HW + 5468896)      // 5646592 ; env interleaved: NBLK*TQ*16 = 5475840
#define OFF_SEND  (OFF_ENV + 5475840)     // 11122432 ; 297600
#define OFF_SINIT (OFF_SEND + 297600)     // 11420032 ; 297600 ; total 11717632 fl = 46.9 MB

struct ScanP {
  float a1[5], b0[5], factor[5], efl2[5], offset[5], init[5], rinit[5];
  float minlvl, corr, scale;
};
struct ModP {
  float pre[12], pim[12], pb0[12], pLre[12], pLim[12];
  float att;
};

typedef float f32x4_t __attribute__((ext_vector_type(4)));

// ---------- combined hp*me FIR (length 1023) ----------
__global__ void k_h1(const float* __restrict__ hp, const float* __restrict__ me,
                     float* __restrict__ h1) {
  int k = blockIdx.x * blockDim.x + threadIdx.x;
  if (k >= H1LEN) return;
  int j0 = max(0, k - (LH - 1));
  int j1 = min(LH - 1, k);
  float acc = 0.f;
  for (int j = j0; j <= j1; ++j) acc += hp[j] * me[k - j];
  h1[k] = acc;
}

// ---------- IHC LP^5 impulse response: (1-a)^5 * C(k+4,4) * a^k ----------
__global__ void k_g5(float l2a, float c5, float* __restrict__ g5) {
  int k = threadIdx.x;  // 128
  float kf = (float)k;
  float binom = (kf + 1.f) * (kf + 2.f) * (kf + 3.f) * (kf + 4.f) * (1.0f / 24.0f);
  g5[k] = c5 * binom * exp2f(kf * l2a);
}

// ---------- conv1: x (*) h1 -> x1,  K=1023, 1 output/thread ----------
__global__ void k_conv1(const float* __restrict__ x, const float* __restrict__ h1,
                        float* __restrict__ x1) {
  __shared__ float xs[256 + 1022];  // 1278
  __shared__ float hs[H1LEN];
  int b = blockIdx.y;
  int t0 = blockIdx.x * 256;
  const float* xb = x + b * T_;
  for (int i = threadIdx.x; i < 1278; i += 256) {
    int g = t0 - 1022 + i;
    xs[i] = (g >= 0 && g < T_) ? xb[g] : 0.f;
  }
  for (int i = threadIdx.x; i < H1LEN; i += 256) hs[i] = h1[i];
  __syncthreads();
  int t = t0 + threadIdx.x;
  if (t >= T_) return;
  float acc = 0.f;
  for (int k = 0; k < H1LEN; ++k) acc = fmaf(hs[k], xs[threadIdx.x + 1022 - k], acc);
  x1[b * T_ + t] = acc;
}

// ---------- conv2: x1 (*) gt[n] -> hw = relu(y), K=2048, 4 outputs/thread ----------
// Filter taps are WAVE-UNIFORM (same hs[k] for all lanes) -> read gt directly
// (uniform base + uniform index scalarizes to s_load; SGPR operand feeds v_fma).
// This halves ds_read_b128 issue, which was the kernel's bottleneck
// (~268M wave-reads x 12cyc vs ~145us of FMA issue).
__global__ __launch_bounds__(C2THR) void k_conv2(const float* __restrict__ x1,
                                                 const float* __restrict__ gt,
                                                 float* __restrict__ hw) {
  const int H = LG - 1;  // 2047
  __shared__ __align__(16) float xs[C2T + LG];  // 2560
  int n = blockIdx.y % NCH, b = blockIdx.y / NCH;
  int t0 = blockIdx.x * C2T;
  const float* xb = x1 + b * T_;
  for (int i = threadIdx.x; i < C2T + LG; i += C2THR) {
    int g = t0 - H + i;
    xs[i] = (g >= 0 && g < T_) ? xb[g] : 0.f;
  }
  __syncthreads();
  const float* gtn = gt + n * LG;
  int base = threadIdx.x * 4;
  float a0 = 0.f, a1 = 0.f, a2 = 0.f, a3 = 0.f;
  float4 hi = *(const float4*)&xs[base + H + 1];  // [base+H+1 .. base+H+4]
  for (int k4 = 0; k4 < LG / 4; ++k4) {
    int k = k4 * 4;
    float4 lo = *(const float4*)&xs[base + H - 3 - k];  // [base+H-3-k .. base+H-k]
    float h0 = gtn[k + 0], h1v = gtn[k + 1], h2 = gtn[k + 2], h3 = gtn[k + 3];
    a0 = fmaf(h0,  lo.w, a0); a1 = fmaf(h0,  hi.x, a1); a2 = fmaf(h0,  hi.y, a2); a3 = fmaf(h0,  hi.z, a3);
    a0 = fmaf(h1v, lo.z, a0); a1 = fmaf(h1v, lo.w, a1); a2 = fmaf(h1v, hi.x, a2); a3 = fmaf(h1v, hi.y, a3);
    a0 = fmaf(h2,  lo.y, a0); a1 = fmaf(h2,  lo.z, a1); a2 = fmaf(h2,  lo.w, a2); a3 = fmaf(h2,  hi.x, a3);
    a0 = fmaf(h3,  lo.x, a0); a1 = fmaf(h3,  lo.y, a1); a2 = fmaf(h3,  lo.z, a2); a3 = fmaf(h3,  lo.w, a3);
    hi = lo;
  }
  float* o = hw + (size_t)(b * NCH + n) * T_;
  int t = t0 + base;
  if (t + 0 < T_) o[t + 0] = fmaxf(a0, 0.f);
  if (t + 1 < T_) o[t + 1] = fmaxf(a1, 0.f);
  if (t + 2 < T_) o[t + 2] = fmaxf(a2, 0.f);
  if (t + 3 < T_) o[t + 3] = fmaxf(a3, 0.f);
}

// ---------- IHC FIR: hw (*) g5 -> env (interleaved), K=128, 4 outputs/thread ----------
// env layout: [blk=bn/4][tq=t/4][s=bn%4][tt=t%4]  (one float4 store per thread)
// g5 taps wave-uniform -> read directly (scalarizes), no LDS staging.
__global__ __launch_bounds__(C2THR) void k_ihc(const float* __restrict__ hw,
                                               const float* __restrict__ g5,
                                               float* __restrict__ env) {
  const int H = IHCK - 1;  // 127
  __shared__ __align__(16) float xs[C2T + IHCK];  // 640
  int bn = blockIdx.y;
  int t0 = blockIdx.x * C2T;
  const float* xb = hw + (size_t)bn * T_;
  for (int i = threadIdx.x; i < C2T + IHCK; i += C2THR) {
    int g = t0 - H + i;
    xs[i] = (g >= 0 && g < T_) ? xb[g] : 0.f;
  }
  __syncthreads();
  int base = threadIdx.x * 4;
  float a0 = 0.f, a1 = 0.f, a2 = 0.f, a3 = 0.f;
  float4 hi = *(const float4*)&xs[base + H + 1];
  for (int k4 = 0; k4 < IHCK / 4; ++k4) {
    int k = k4 * 4;
    float4 lo = *(const float4*)&xs[base + H - 3 - k];
    float h0 = g5[k + 0], h1v = g5[k + 1], h2 = g5[k + 2], h3 = g5[k + 3];
    a0 = fmaf(h0,  lo.w, a0); a1 = fmaf(h0,  hi.x, a1); a2 = fmaf(h0,  hi.y, a2); a3 = fmaf(h0,  hi.z, a3);
    a0 = fmaf(h1v, lo.z, a0); a1 = fmaf(h1v, lo.w, a1); a2 = fmaf(h1v, hi.x, a2); a3 = fmaf(h1v, hi.y, a3);
    a0 = fmaf(h2,  lo.y, a0); a1 = fmaf(h2,  lo.z, a1); a2 = fmaf(h2,  lo.w, a2); a3 = fmaf(h2,  hi.x, a3);
    a0 = fmaf(h3,  lo.x, a0); a1 = fmaf(h3,  lo.y, a1); a2 = fmaf(h3,  lo.z, a2); a3 = fmaf(h3,  lo.w, a3);
    hi = lo;
  }
  int t = t0 + base;
  if (t < T_) {  // last quad may carry 2 junk lanes (t=22050/22051) -> never affect stored outputs
    int blk = bn >> 2, s = bn & 3, tq = t >> 2;
    float4* o4 = (float4*)(env + ((size_t)(blk * TQ + tq) * 4 + s) * 4);
    *o4 = make_float4(a0, a1, a2, a3);
  }
}

// ---------- adaptation loops: systolic 5-lane pipeline, 1 seq per 16-lane row ----------
// Lane q (=lane&15) = stage j for q<5; q>=5 idle. Stage j at group k processes t=k-j.
// tmp passes j-1 -> j via DPP row_shr:1; lane q=0 (stage 0) gets `old` = env value
// (bound_ctrl=false) -- no select on the recurrence chain.
//
// Memory pipeline: opaque inline-asm global_load_dwordx4 into an 8-deep
// statically-named register queue (the compiler collapses C-level prefetch),
// counted s_waitcnt vmcnt(14) (load consumed now was issued 8 substeps ago;
// 7 loads + 7 stores after it in the VMEM FIFO). Prologue drains vmcnt(0) once.
// sched_barrier(0) after each wait keeps hipcc from hoisting register-only
// consumers past the inline-asm wait.  [EXACT R2 kernel: measured 811us, passed.]
#define GLD0(DST, PTR)  asm volatile("global_load_dwordx4 %0, %1, off"            : "=v"(DST) : "v"(PTR) : "memory")
#define GLD(DST, PTR, OFFB) \
  asm volatile("global_load_dwordx4 %0, %1, off offset:" #OFFB : "=v"(DST) : "v"(PTR) : "memory")
#define VMWAIT(N) do { asm volatile("s_waitcnt vmcnt(" #N ")" ::: "memory"); \
                       __builtin_amdgcn_sched_barrier(0); } while (0)

__global__ __launch_bounds__(64, 1) void k_scan(const float* __restrict__ env,
                                                float* __restrict__ ad, ScanP p) {
  const int lane = threadIdx.x;
  const int row = lane >> 4, q = lane & 15;
  const int seq = blockIdx.x * 4 + row;
  const bool is4 = (q == 4);
  const float* eb = env + (size_t)blockIdx.x * TQ * 16 + row * 4;  // +tq*16 per quad
  float* o = ad + (size_t)seq * ADP;

#define SEL5(A) (q==0 ? (A)[0] : q==1 ? (A)[1] : q==2 ? (A)[2] : q==3 ? (A)[3] : (A)[4])
  const float A1  = SEL5(p.a1),   B0  = SEL5(p.b0), FAC = SEL5(p.factor);
  const float EF  = SEL5(p.efl2), NEF = -EF,        NOFF = -SEL5(p.offset);
  float st = SEL5(p.init);
  float r  = SEL5(p.rinit);
#undef SEL5
  const float SC = p.scale, NCS = -p.corr * p.scale, ML = p.minlvl;

  float a1st = A1 * st;   // off-critical-path precompute of a1*st for the state fma
  float tmp = 0.f;
  float o0 = 0.f, o1 = 0.f, o2 = 0.f, o3 = 0.f;

  // tmp = min(v, lim) is exact away from v==1 (lim(v)=1+m*tanh((v-1)/m) crosses
  // v only there; ~1 ulp at crossover, same tolerance class as rcp divide).
#define BODY(EV)                                                              \
    float evc = fmaxf((EV), ML);                                              \
    float tin = __int_as_float(__builtin_amdgcn_update_dpp(                   \
        __float_as_int(evc), __float_as_int(tmp), 0x111, 0xF, 0xF, false));   \
    float v   = tin * r;                                                      \
    float ex  = __builtin_amdgcn_exp2f(fmaf(EF, v, NEF));                     \
    float lim = fmaf(FAC, __builtin_amdgcn_rcpf(1.0f + ex), NOFF);            \
    tmp = fminf(v, lim);

#define STEP_FILL(EV, K)                                                      \
  { BODY(EV)                                                                  \
    float nst = fmaf(B0, tmp, a1st);                                          \
    st = ((K) >= q) ? nst : st;                                               \
    a1st = A1 * st;                                                           \
    r  = __builtin_amdgcn_rcpf(st); }

#define STEP(EV, OSLOT)                                                       \
  { BODY(EV)                                                                  \
    st = fmaf(B0, tmp, a1st);                                                 \
    a1st = A1 * st;                                                           \
    r  = __builtin_amdgcn_rcpf(st);                                           \
    OSLOT = fmaf(tmp, SC, NCS); }

  // 8-deep opaque prefetch queue + fill quad
  f32x4_t bF, b0, b1, b2, b3, b4, b5, b6, b7;
  GLD0(bF, eb);
  GLD(b0, eb, 64);   GLD(b1, eb, 128);  GLD(b2, eb, 192);  GLD(b3, eb, 256);
  GLD(b4, eb, 320);  GLD(b5, eb, 384);  GLD(b6, eb, 448);  GLD(b7, eb, 512);
  VMWAIT(0);

  // pipeline fill: groups 0..3 (stage-4 t < 0, no stores), quad 0
  STEP_FILL(bF.x, 0) STEP_FILL(bF.y, 1) STEP_FILL(bF.z, 2) STEP_FILL(bF.w, 3)

  const float* pld = eb + 9 * 16;  // next quad to load (quad 9)
  float* po = o;                   // next store base (t = 32*j)

#define SUBSTEP(BUF, FOFF, BOFF)                                              \
    VMWAIT(14);                                                               \
    STEP(BUF.x, o0) STEP(BUF.y, o1) STEP(BUF.z, o2) STEP(BUF.w, o3)           \
    if (is4) *(float4*)(po + FOFF) = make_float4(o0, o1, o2, o3);             \
    GLD(BUF, pld, BOFF);

  // main: 689 iterations x 8 quads = quads 1..5512, groups 4..22051 -> t=0..22047.
  // Refills run to quad 5520 (64B past this row's TQ=5520 region -> lands in the
  // next block's region / OFF_SEND scratch: allocated, dead data).
  for (int j = 0; j < 689; ++j) {
    SUBSTEP(b0,  0,   0)
    SUBSTEP(b1,  4,  64)
    SUBSTEP(b2,  8, 128)
    SUBSTEP(b3, 12, 192)
    SUBSTEP(b4, 16, 256)
    SUBSTEP(b5, 20, 320)
    SUBSTEP(b6, 24, 384)
    SUBSTEP(b7, 28, 448)
    pld += 8 * 16;
    po  += 32;
  }
#undef SUBSTEP

  // drain: groups 22052, 22053 -> t = 22048, 22049 (+2 pad floats, row pitch 22052)
  STEP(0.f, o0) STEP(0.f, o1)
  if (is4) *(float4*)(o + 22048) = make_float4(o0, o1, o2, o3);
#undef STEP
#undef STEP_FILL
#undef BODY
}

// ---------- modulation filterbank, chunk-parallel linear scan ----------
__global__ void k_modA(const float* __restrict__ ad, float2* __restrict__ send, ModP mp) {
  int id = blockIdx.x * 256 + threadIdx.x;
  if (id >= MODC * BN * MM) return;
  int m = id % MM, bn = (id / MM) % BN, c = id / (MM * BN);
  const float* a = ad + (size_t)bn * ADP + c * MODL;
  float pre = mp.pre[m], pim = mp.pim[m], b0 = mp.pb0[m];
  float sre = 0.f, sim = 0.f;
  for (int i = 0; i < MODL; ++i) {
    float xv = a[i];
    float nre = fmaf(pre, sre, fmaf(-pim, sim, b0 * xv));
    sim = fmaf(pre, sim, pim * sre);
    sre = nre;
  }
  send[id] = make_float2(sre, sim);
}

__global__ void k_modB(const float2* __restrict__ send, float2* __restrict__ sinit, ModP mp) {
  int id = blockIdx.x * blockDim.x + threadIdx.x;
  if (id >= BN * MM) return;
  int m = id % MM;
  float pLre = mp.pLre[m], pLim = mp.pLim[m];
  float Sre = 0.f, Sim = 0.f;
  for (int c = 0; c < MODC; ++c) {
    int idx = c * BN * MM + id;
    sinit[idx] = make_float2(Sre, Sim);
    float2 se = send[idx];
    float nre = pLre * Sre - pLim * Sim + se.x;
    Sim = pLre * Sim + pLim * Sre + se.y;
    Sre = nre;
  }
}

__global__ void k_modC(const float* __restrict__ ad, const float2* __restrict__ sinit,
                       float* __restrict__ out, ModP mp) {
  int id = blockIdx.x * 256 + threadIdx.x;
  if (id >= MODC * BN * MM) return;
  int m = id % MM, bn = (id / MM) % BN, c = id / (MM * BN);
  const float* a = ad + (size_t)bn * ADP + c * MODL;
  float* o = out + ((size_t)bn * MM + m) * T_ + c * MODL;
  float2 s0 = sinit[id];
  float sre = s0.x, sim = s0.y;
  float pre = mp.pre[m], pim = mp.pim[m], b0 = mp.pb0[m], att = mp.att;
  bool low = (m < 3);  // mfc <= 10 Hz
  for (int i = 0; i < MODL; ++i) {
    float xv = a[i];
    float nre = fmaf(pre, sre, fmaf(-pim, sim, b0 * xv));
    sim = fmaf(pre, sim, pim * sre);
    sre = nre;
    float mag = att * sqrtf(fmaf(sre, sre, fmaf(sim, sim, 1e-12f)));
    o[i] = low ? sre : mag;
  }
}

extern "C" void kernel_launch(void* const* d_in, const int* in_sizes, int n_in,
                              void* d_out, int out_size, void* d_ws, size_t ws_size,
                              hipStream_t stream) {
  const float* x  = (const float*)d_in[0];
  const float* hp = (const float*)d_in[1];
  const float* me = (const float*)d_in[2];
  const float* gt = (const float*)d_in[3];
  float* ws  = (float*)d_ws;
  float* out = (float*)d_out;

  // ---- host-side constant computation (double precision) ----
  ScanP sp;
  const double taus[5] = {0.005, 0.05, 0.129, 0.253, 0.5};
  for (int j = 0; j < 5; ++j) {
    double a1 = exp(-1.0 / (FS_ * taus[j]));
    double init = pow(1e-5, pow(2.0, -(double)(j + 1)));
    double maxv = (1.0 - init * init) * 5.0 - 1.0;
    sp.a1[j] = (float)a1;
    sp.b0[j] = (float)(1.0 - a1);
    sp.factor[j] = (float)(2.0 * maxv);
    sp.efl2[j] = (float)(-2.0 / maxv * 1.4426950408889634);  // expfac * log2(e)
    sp.offset[j] = (float)(maxv - 1.0);
    sp.init[j] = (float)init;
    sp.rinit[j] = (float)(1.0 / init);
  }
  sp.minlvl = 1e-5f;
  double corr = pow(1e-5, pow(2.0, -5.0));
  sp.corr = (float)corr;
  sp.scale = (float)(100.0 / (1.0 - corr));

  ModP mp;
  const double mfc[12] = {2.5, 5.0, 10.0, 16.7, 27.8, 46.3, 77.2, 128.6, 214.3, 357.2, 595.4, 992.3};
  for (int m = 0; m < 12; ++m) {
    double r = exp(-M_PI * (mfc[m] / 2.0) / FS_);
    double th = 2.0 * M_PI * mfc[m] / FS_;
    mp.pre[m] = (float)(r * cos(th));
    mp.pim[m] = (float)(r * sin(th));
    mp.pb0[m] = (float)(1.0 - r);
    double rL = pow(r, (double)MODL);
    mp.pLre[m] = (float)(rL * cos((double)MODL * th));
    mp.pLim[m] = (float)(rL * sin((double)MODL * th));
  }
  mp.att = (float)(1.0 / sqrt(2.0));

  double alp = exp(-2.0 * M_PI * 2000.0 / FS_);
  float l2a = (float)(log(alp) * 1.4426950408889634);
  float c5  = (float)pow(1.0 - alp, 5.0);

  float* h1  = ws + OFF_H1;
  float* g5  = ws + OFF_G5;
  float* x1  = ws + OFF_X1;
  float* hw  = ws + OFF_HW;
  float* env = ws + OFF_ENV;
  float* ad  = ws + OFF_AD;  // aliases hw (dead after IHC)
  float2* send  = (float2*)(ws + OFF_SEND);
  float2* sinit = (float2*)(ws + OFF_SINIT);

  k_h1<<<dim3(2), dim3(512), 0, stream>>>(hp, me, h1);
  k_g5<<<dim3(1), dim3(128), 0, stream>>>(l2a, c5, g5);
  k_conv1<<<dim3(87, B_), dim3(256), 0, stream>>>(x, h1, x1);
  k_conv2<<<dim3((T_ + C2T - 1) / C2T, BN), dim3(C2THR), 0, stream>>>(x1, gt, hw);
  k_ihc<<<dim3((T_ + C2T - 1) / C2T, BN), dim3(C2THR), 0, stream>>>(hw, g5, env);
  k_scan<<<dim3(NBLK), dim3(64), 0, stream>>>(env, ad, sp);  // 4 seqs/wave, 5-lane systolic
  int nmod = MODC * BN * MM;
  k_modA<<<dim3((nmod + 255) / 256), dim3(256), 0, stream>>>(ad, send, mp);
  k_modB<<<dim3((BN * MM + 255) / 256), dim3(256), 0, stream>>>(send, sinit, mp);
  k_modC<<<dim3((nmod + 255) / 256), dim3(256), 0, stream>>>(ad, sinit, out, mp);
}

// Round 6
// 1693.998 us; speedup vs baseline: 1.1273x; 1.0424x over previous
//
#include <hip/hip_runtime.h>
#include <math.h>

#define FS_   44100.0
#define B_    8
#define T_    22050
#define NCH   31
#define LG    2048
#define LH    512
#define MM    12
#define BN    248          // B_*NCH

#define H1LEN 1023         // LH+LH-1

#define C2T   512          // t-tile for conv2/ihc
#define C2THR 128          // threads (each does 4 consecutive t)

#define IHCK  128          // IHC FIR taps

#define MODL  441
#define MODC  50           // MODL*MODC == T_
#define MCT   63           // modC tile width (441 = 7*63)

#define NBLK  62           // k_scan blocks: 4 seqs per wave
#define TQ    5520         // env time-quads per seq (22080/4, padded)
#define ADP   22052        // ad row pitch (multiple of 4 floats -> 16B rows)

// ---- workspace layout (in floats) ----
#define OFF_H1    0                       // 1024
#define OFF_G5    1024                    // 256
#define OFF_X1    1280                    // 176400 (pad to 177696)
#define OFF_HW    177696                  // hw: BN*T_ = 5468400 ; ad alias: BN*ADP = 5468896
#define OFF_AD    OFF_HW
#define OFF_ENV   (OFF_HW + 5468896)      // 5646592 ; env interleaved: NBLK*TQ*16 = 5475840
#define OFF_SEND  (OFF_ENV + 5475840)     // 11122432 ; 297600
#define OFF_SINIT (OFF_SEND + 297600)     // 11420032 ; 297600 ; total 11717632 fl = 46.9 MB

struct ScanP {
  float a1[5], b0[5], factor[5], efl2[5], offset[5], init[5], rinit[5];
  float minlvl, corr, scale;
};
struct ModP {
  float pre[12], pim[12], pb0[12], pLre[12], pLim[12];
  float att;
};

typedef float f32x4_t __attribute__((ext_vector_type(4)));

// ---------- combined hp*me FIR (length 1023) ----------
__global__ void k_h1(const float* __restrict__ hp, const float* __restrict__ me,
                     float* __restrict__ h1) {
  int k = blockIdx.x * blockDim.x + threadIdx.x;
  if (k >= H1LEN) return;
  int j0 = max(0, k - (LH - 1));
  int j1 = min(LH - 1, k);
  float acc = 0.f;
  for (int j = j0; j <= j1; ++j) acc += hp[j] * me[k - j];
  h1[k] = acc;
}

// ---------- IHC LP^5 impulse response: (1-a)^5 * C(k+4,4) * a^k ----------
__global__ void k_g5(float l2a, float c5, float* __restrict__ g5) {
  int k = threadIdx.x;  // 128
  float kf = (float)k;
  float binom = (kf + 1.f) * (kf + 2.f) * (kf + 3.f) * (kf + 4.f) * (1.0f / 24.0f);
  g5[k] = c5 * binom * exp2f(kf * l2a);
}

// ---------- conv1: x (*) h1 -> x1,  K=1023, 1 output/thread ----------
// h1 taps are wave-uniform -> read global directly (scalarizes to s_load),
// halving the LDS issue of the serial tap loop (same verified trick as conv2).
__global__ void k_conv1(const float* __restrict__ x, const float* __restrict__ h1,
                        float* __restrict__ x1) {
  __shared__ float xs[256 + 1022];  // 1278
  int b = blockIdx.y;
  int t0 = blockIdx.x * 256;
  const float* xb = x + b * T_;
  for (int i = threadIdx.x; i < 1278; i += 256) {
    int g = t0 - 1022 + i;
    xs[i] = (g >= 0 && g < T_) ? xb[g] : 0.f;
  }
  __syncthreads();
  int t = t0 + threadIdx.x;
  if (t >= T_) return;
  float acc = 0.f;
  for (int k = 0; k < H1LEN; ++k) acc = fmaf(h1[k], xs[threadIdx.x + 1022 - k], acc);
  x1[b * T_ + t] = acc;
}

// ---------- conv2: x1 (*) gt[n] -> hw = relu(y), K=2048, 4 outputs/thread ----------
// Filter taps are WAVE-UNIFORM (same hs[k] for all lanes) -> read gt directly
// (uniform base + uniform index scalarizes to s_load; SGPR operand feeds v_fma).
__global__ __launch_bounds__(C2THR) void k_conv2(const float* __restrict__ x1,
                                                 const float* __restrict__ gt,
                                                 float* __restrict__ hw) {
  const int H = LG - 1;  // 2047
  __shared__ __align__(16) float xs[C2T + LG];  // 2560
  int n = blockIdx.y % NCH, b = blockIdx.y / NCH;
  int t0 = blockIdx.x * C2T;
  const float* xb = x1 + b * T_;
  for (int i = threadIdx.x; i < C2T + LG; i += C2THR) {
    int g = t0 - H + i;
    xs[i] = (g >= 0 && g < T_) ? xb[g] : 0.f;
  }
  __syncthreads();
  const float* gtn = gt + n * LG;
  int base = threadIdx.x * 4;
  float a0 = 0.f, a1 = 0.f, a2 = 0.f, a3 = 0.f;
  float4 hi = *(const float4*)&xs[base + H + 1];  // [base+H+1 .. base+H+4]
  for (int k4 = 0; k4 < LG / 4; ++k4) {
    int k = k4 * 4;
    float4 lo = *(const float4*)&xs[base + H - 3 - k];  // [base+H-3-k .. base+H-k]
    float h0 = gtn[k + 0], h1v = gtn[k + 1], h2 = gtn[k + 2], h3 = gtn[k + 3];
    a0 = fmaf(h0,  lo.w, a0); a1 = fmaf(h0,  hi.x, a1); a2 = fmaf(h0,  hi.y, a2); a3 = fmaf(h0,  hi.z, a3);
    a0 = fmaf(h1v, lo.z, a0); a1 = fmaf(h1v, lo.w, a1); a2 = fmaf(h1v, hi.x, a2); a3 = fmaf(h1v, hi.y, a3);
    a0 = fmaf(h2,  lo.y, a0); a1 = fmaf(h2,  lo.z, a1); a2 = fmaf(h2,  lo.w, a2); a3 = fmaf(h2,  hi.x, a3);
    a0 = fmaf(h3,  lo.x, a0); a1 = fmaf(h3,  lo.y, a1); a2 = fmaf(h3,  lo.z, a2); a3 = fmaf(h3,  lo.w, a3);
    hi = lo;
  }
  float* o = hw + (size_t)(b * NCH + n) * T_;
  int t = t0 + base;
  if (t + 0 < T_) o[t + 0] = fmaxf(a0, 0.f);
  if (t + 1 < T_) o[t + 1] = fmaxf(a1, 0.f);
  if (t + 2 < T_) o[t + 2] = fmaxf(a2, 0.f);
  if (t + 3 < T_) o[t + 3] = fmaxf(a3, 0.f);
}

// ---------- IHC FIR: hw (*) g5 -> env (interleaved), K=128, 4 outputs/thread ----------
// env layout: [blk=bn/4][tq=t/4][s=bn%4][tt=t%4]  (one float4 store per thread)
// g5 taps wave-uniform -> read directly (scalarizes), no LDS staging.
__global__ __launch_bounds__(C2THR) void k_ihc(const float* __restrict__ hw,
                                               const float* __restrict__ g5,
                                               float* __restrict__ env) {
  const int H = IHCK - 1;  // 127
  __shared__ __align__(16) float xs[C2T + IHCK];  // 640
  int bn = blockIdx.y;
  int t0 = blockIdx.x * C2T;
  const float* xb = hw + (size_t)bn * T_;
  for (int i = threadIdx.x; i < C2T + IHCK; i += C2THR) {
    int g = t0 - H + i;
    xs[i] = (g >= 0 && g < T_) ? xb[g] : 0.f;
  }
  __syncthreads();
  int base = threadIdx.x * 4;
  float a0 = 0.f, a1 = 0.f, a2 = 0.f, a3 = 0.f;
  float4 hi = *(const float4*)&xs[base + H + 1];
  for (int k4 = 0; k4 < IHCK / 4; ++k4) {
    int k = k4 * 4;
    float4 lo = *(const float4*)&xs[base + H - 3 - k];
    float h0 = g5[k + 0], h1v = g5[k + 1], h2 = g5[k + 2], h3 = g5[k + 3];
    a0 = fmaf(h0,  lo.w, a0); a1 = fmaf(h0,  hi.x, a1); a2 = fmaf(h0,  hi.y, a2); a3 = fmaf(h0,  hi.z, a3);
    a0 = fmaf(h1v, lo.z, a0); a1 = fmaf(h1v, lo.w, a1); a2 = fmaf(h1v, hi.x, a2); a3 = fmaf(h1v, hi.y, a3);
    a0 = fmaf(h2,  lo.y, a0); a1 = fmaf(h2,  lo.z, a1); a2 = fmaf(h2,  lo.w, a2); a3 = fmaf(h2,  hi.x, a3);
    a0 = fmaf(h3,  lo.x, a0); a1 = fmaf(h3,  lo.y, a1); a2 = fmaf(h3,  lo.z, a2); a3 = fmaf(h3,  lo.w, a3);
    hi = lo;
  }
  int t = t0 + base;
  if (t < T_) {  // last quad may carry 2 junk lanes (t=22050/22051) -> never affect stored outputs
    int blk = bn >> 2, s = bn & 3, tq = t >> 2;
    float4* o4 = (float4*)(env + ((size_t)(blk * TQ + tq) * 4 + s) * 4);
    *o4 = make_float4(a0, a1, a2, a3);
  }
}

// ---------- adaptation loops: systolic 5-lane pipeline, 1 seq per 16-lane row ----------
// Lane q (=lane&15) = stage j for q<5; q>=5 idle. Stage j at group k processes t=k-j.
// tmp passes j-1 -> j via DPP row_shr:1; lane q=0 (stage 0) gets `old` = env value
// (bound_ctrl=false) -- no select on the recurrence chain.
//
// Memory pipeline: opaque inline-asm global_load_dwordx4 into an 8-deep
// statically-named register queue (the compiler collapses C-level prefetch),
// counted s_waitcnt vmcnt(14) (load consumed now was issued 8 substeps ago;
// 7 loads + 7 stores after it in the VMEM FIFO). Prologue drains vmcnt(0) once.
// sched_barrier(0) after each wait keeps hipcc from hoisting register-only
// consumers past the inline-asm wait.  [EXACT R2 kernel: measured 810us, passed.]
#define GLD0(DST, PTR)  asm volatile("global_load_dwordx4 %0, %1, off"            : "=v"(DST) : "v"(PTR) : "memory")
#define GLD(DST, PTR, OFFB) \
  asm volatile("global_load_dwordx4 %0, %1, off offset:" #OFFB : "=v"(DST) : "v"(PTR) : "memory")
#define VMWAIT(N) do { asm volatile("s_waitcnt vmcnt(" #N ")" ::: "memory"); \
                       __builtin_amdgcn_sched_barrier(0); } while (0)

__global__ __launch_bounds__(64, 1) void k_scan(const float* __restrict__ env,
                                                float* __restrict__ ad, ScanP p) {
  const int lane = threadIdx.x;
  const int row = lane >> 4, q = lane & 15;
  const int seq = blockIdx.x * 4 + row;
  const bool is4 = (q == 4);
  const float* eb = env + (size_t)blockIdx.x * TQ * 16 + row * 4;  // +tq*16 per quad
  float* o = ad + (size_t)seq * ADP;

#define SEL5(A) (q==0 ? (A)[0] : q==1 ? (A)[1] : q==2 ? (A)[2] : q==3 ? (A)[3] : (A)[4])
  const float A1  = SEL5(p.a1),   B0  = SEL5(p.b0), FAC = SEL5(p.factor);
  const float EF  = SEL5(p.efl2), NEF = -EF,        NOFF = -SEL5(p.offset);
  float st = SEL5(p.init);
  float r  = SEL5(p.rinit);
#undef SEL5
  const float SC = p.scale, NCS = -p.corr * p.scale, ML = p.minlvl;

  float a1st = A1 * st;   // off-critical-path precompute of a1*st for the state fma
  float tmp = 0.f;
  float o0 = 0.f, o1 = 0.f, o2 = 0.f, o3 = 0.f;

  // tmp = min(v, lim) is exact away from v==1 (lim(v)=1+m*tanh((v-1)/m) crosses
  // v only there; ~1 ulp at crossover, same tolerance class as rcp divide).
#define BODY(EV)                                                              \
    float evc = fmaxf((EV), ML);                                              \
    float tin = __int_as_float(__builtin_amdgcn_update_dpp(                   \
        __float_as_int(evc), __float_as_int(tmp), 0x111, 0xF, 0xF, false));   \
    float v   = tin * r;                                                      \
    float ex  = __builtin_amdgcn_exp2f(fmaf(EF, v, NEF));                     \
    float lim = fmaf(FAC, __builtin_amdgcn_rcpf(1.0f + ex), NOFF);            \
    tmp = fminf(v, lim);

#define STEP_FILL(EV, K)                                                      \
  { BODY(EV)                                                                  \
    float nst = fmaf(B0, tmp, a1st);                                          \
    st = ((K) >= q) ? nst : st;                                               \
    a1st = A1 * st;                                                           \
    r  = __builtin_amdgcn_rcpf(st); }

#define STEP(EV, OSLOT)                                                       \
  { BODY(EV)                                                                  \
    st = fmaf(B0, tmp, a1st);                                                 \
    a1st = A1 * st;                                                           \
    r  = __builtin_amdgcn_rcpf(st);                                           \
    OSLOT = fmaf(tmp, SC, NCS); }

  // 8-deep opaque prefetch queue + fill quad
  f32x4_t bF, b0, b1, b2, b3, b4, b5, b6, b7;
  GLD0(bF, eb);
  GLD(b0, eb, 64);   GLD(b1, eb, 128);  GLD(b2, eb, 192);  GLD(b3, eb, 256);
  GLD(b4, eb, 320);  GLD(b5, eb, 384);  GLD(b6, eb, 448);  GLD(b7, eb, 512);
  VMWAIT(0);

  // pipeline fill: groups 0..3 (stage-4 t < 0, no stores), quad 0
  STEP_FILL(bF.x, 0) STEP_FILL(bF.y, 1) STEP_FILL(bF.z, 2) STEP_FILL(bF.w, 3)

  const float* pld = eb + 9 * 16;  // next quad to load (quad 9)
  float* po = o;                   // next store base (t = 32*j)

#define SUBSTEP(BUF, FOFF, BOFF)                                              \
    VMWAIT(14);                                                               \
    STEP(BUF.x, o0) STEP(BUF.y, o1) STEP(BUF.z, o2) STEP(BUF.w, o3)           \
    if (is4) *(float4*)(po + FOFF) = make_float4(o0, o1, o2, o3);             \
    GLD(BUF, pld, BOFF);

  // main: 689 iterations x 8 quads = quads 1..5512, groups 4..22051 -> t=0..22047.
  // Refills run to quad 5520 (64B past this row's TQ=5520 region -> lands in the
  // next block's region / OFF_SEND scratch: allocated, dead data).
  for (int j = 0; j < 689; ++j) {
    SUBSTEP(b0,  0,   0)
    SUBSTEP(b1,  4,  64)
    SUBSTEP(b2,  8, 128)
    SUBSTEP(b3, 12, 192)
    SUBSTEP(b4, 16, 256)
    SUBSTEP(b5, 20, 320)
    SUBSTEP(b6, 24, 384)
    SUBSTEP(b7, 28, 448)
    pld += 8 * 16;
    po  += 32;
  }
#undef SUBSTEP

  // drain: groups 22052, 22053 -> t = 22048, 22049 (+2 pad floats, row pitch 22052)
  STEP(0.f, o0) STEP(0.f, o1)
  if (is4) *(float4*)(o + 22048) = make_float4(o0, o1, o2, o3);
#undef STEP
#undef STEP_FILL
#undef BODY
}

// ---------- modulation filterbank, chunk-parallel linear scan ----------
__global__ void k_modA(const float* __restrict__ ad, float2* __restrict__ send, ModP mp) {
  int id = blockIdx.x * 256 + threadIdx.x;
  if (id >= MODC * BN * MM) return;
  int m = id % MM, bn = (id / MM) % BN, c = id / (MM * BN);
  const float* a = ad + (size_t)bn * ADP + c * MODL;
  float pre = mp.pre[m], pim = mp.pim[m], b0 = mp.pb0[m];
  float sre = 0.f, sim = 0.f;
  for (int i = 0; i < MODL; ++i) {
    float xv = a[i];
    float nre = fmaf(pre, sre, fmaf(-pim, sim, b0 * xv));
    sim = fmaf(pre, sim, pim * sre);
    sre = nre;
  }
  send[id] = make_float2(sre, sim);
}

__global__ void k_modB(const float2* __restrict__ send, float2* __restrict__ sinit, ModP mp) {
  int id = blockIdx.x * blockDim.x + threadIdx.x;
  if (id >= BN * MM) return;
  int m = id % MM;
  float pLre = mp.pLre[m], pLim = mp.pLim[m];
  float Sre = 0.f, Sim = 0.f;
  for (int c = 0; c < MODC; ++c) {
    int idx = c * BN * MM + id;
    sinit[idx] = make_float2(Sre, Sim);
    float2 se = send[idx];
    float nre = pLre * Sre - pLim * Sim + se.x;
    Sim = pLre * Sim + pLim * Sre + se.y;
    Sre = nre;
  }
}

// ---------- modC: recurrence + COALESCED writes via LDS transpose ----------
// Old pattern: consecutive lanes differ in m -> wave stores scatter to 64
// distinct cachelines (T_ stride) per instruction, ~65.6M line-touches total.
// New: block = 256 consecutive (bn,m) rows at fixed c. 7 tiles of 63 outputs
// (441 = 7*63) buffered in LDS [256][63] (stride 63 = -1 mod 32 -> 2-way bank
// aliasing on compute writes = free; writeback reads row-major = conflict-free).
// Writeback: wave w writes rows 64w..64w+63; lanes 0..62 at consecutive
// addresses -> 1-2 cachelines per store instruction. Arithmetic & order identical.
__global__ __launch_bounds__(256) void k_modC(const float* __restrict__ ad,
                                              const float2* __restrict__ sinit,
                                              float* __restrict__ out, ModP mp) {
  __shared__ float tile[256][MCT];  // 63 KB
  const int tid = threadIdx.x;
  const int c = blockIdx.y;
  const int idc = blockIdx.x * 256 + tid;      // bn*MM + m
  const bool act = idc < BN * MM;
  const int idcc = act ? idc : 0;
  const int m = idcc % MM, bn = idcc / MM;
  const float* a = ad + (size_t)bn * ADP + c * MODL;
  float2 s0 = sinit[c * BN * MM + idcc];
  float sre = s0.x, sim = s0.y;
  const float pre = mp.pre[m], pim = mp.pim[m], b0 = mp.pb0[m], att = mp.att;
  const bool low = (m < 3);  // mfc <= 10 Hz
  const int wv = tid >> 6, ln = tid & 63;
  for (int tb = 0; tb < 7; ++tb) {
    for (int i = 0; i < MCT; ++i) {
      float xv = a[tb * MCT + i];
      float nre = fmaf(pre, sre, fmaf(-pim, sim, b0 * xv));
      sim = fmaf(pre, sim, pim * sre);
      sre = nre;
      float mag = att * sqrtf(fmaf(sre, sre, fmaf(sim, sim, 1e-12f)));
      tile[tid][i] = low ? sre : mag;
    }
    __syncthreads();
    if (ln < MCT) {
      for (int rr = 0; rr < 64; ++rr) {
        int rowi = (wv << 6) + rr;
        int gid = blockIdx.x * 256 + rowi;
        if (gid < BN * MM)
          out[(size_t)gid * T_ + c * MODL + tb * MCT + ln] = tile[rowi][ln];
      }
    }
    __syncthreads();
  }
}

extern "C" void kernel_launch(void* const* d_in, const int* in_sizes, int n_in,
                              void* d_out, int out_size, void* d_ws, size_t ws_size,
                              hipStream_t stream) {
  const float* x  = (const float*)d_in[0];
  const float* hp = (const float*)d_in[1];
  const float* me = (const float*)d_in[2];
  const float* gt = (const float*)d_in[3];
  float* ws  = (float*)d_ws;
  float* out = (float*)d_out;

  // ---- host-side constant computation (double precision) ----
  ScanP sp;
  const double taus[5] = {0.005, 0.05, 0.129, 0.253, 0.5};
  for (int j = 0; j < 5; ++j) {
    double a1 = exp(-1.0 / (FS_ * taus[j]));
    double init = pow(1e-5, pow(2.0, -(double)(j + 1)));
    double maxv = (1.0 - init * init) * 5.0 - 1.0;
    sp.a1[j] = (float)a1;
    sp.b0[j] = (float)(1.0 - a1);
    sp.factor[j] = (float)(2.0 * maxv);
    sp.efl2[j] = (float)(-2.0 / maxv * 1.4426950408889634);  // expfac * log2(e)
    sp.offset[j] = (float)(maxv - 1.0);
    sp.init[j] = (float)init;
    sp.rinit[j] = (float)(1.0 / init);
  }
  sp.minlvl = 1e-5f;
  double corr = pow(1e-5, pow(2.0, -5.0));
  sp.corr = (float)corr;
  sp.scale = (float)(100.0 / (1.0 - corr));

  ModP mp;
  const double mfc[12] = {2.5, 5.0, 10.0, 16.7, 27.8, 46.3, 77.2, 128.6, 214.3, 357.2, 595.4, 992.3};
  for (int m = 0; m < 12; ++m) {
    double r = exp(-M_PI * (mfc[m] / 2.0) / FS_);
    double th = 2.0 * M_PI * mfc[m] / FS_;
    mp.pre[m] = (float)(r * cos(th));
    mp.pim[m] = (float)(r * sin(th));
    mp.pb0[m] = (float)(1.0 - r);
    double rL = pow(r, (double)MODL);
    mp.pLre[m] = (float)(rL * cos((double)MODL * th));
    mp.pLim[m] = (float)(rL * sin((double)MODL * th));
  }
  mp.att = (float)(1.0 / sqrt(2.0));

  double alp = exp(-2.0 * M_PI * 2000.0 / FS_);
  float l2a = (float)(log(alp) * 1.4426950408889634);
  float c5  = (float)pow(1.0 - alp, 5.0);

  float* h1  = ws + OFF_H1;
  float* g5  = ws + OFF_G5;
  float* x1  = ws + OFF_X1;
  float* hw  = ws + OFF_HW;
  float* env = ws + OFF_ENV;
  float* ad  = ws + OFF_AD;  // aliases hw (dead after IHC)
  float2* send  = (float2*)(ws + OFF_SEND);
  float2* sinit = (float2*)(ws + OFF_SINIT);

  k_h1<<<dim3(2), dim3(512), 0, stream>>>(hp, me, h1);
  k_g5<<<dim3(1), dim3(128), 0, stream>>>(l2a, c5, g5);
  k_conv1<<<dim3(87, B_), dim3(256), 0, stream>>>(x, h1, x1);
  k_conv2<<<dim3((T_ + C2T - 1) / C2T, BN), dim3(C2THR), 0, stream>>>(x1, gt, hw);
  k_ihc<<<dim3((T_ + C2T - 1) / C2T, BN), dim3(C2THR), 0, stream>>>(hw, g5, env);
  k_scan<<<dim3(NBLK), dim3(64), 0, stream>>>(env, ad, sp);  // 4 seqs/wave, 5-lane systolic
  int nmod = MODC * BN * MM;
  k_modA<<<dim3((nmod + 255) / 256), dim3(256), 0, stream>>>(ad, send, mp);
  k_modB<<<dim3((BN * MM + 255) / 256), dim3(256), 0, stream>>>(send, sinit, mp);
  k_modC<<<dim3((BN * MM + 255) / 256, MODC), dim3(256), 0, stream>>>(ad, sinit, out, mp);
}

// Round 7
// 1684.357 us; speedup vs baseline: 1.1337x; 1.0057x over previous
//
#include <hip/hip_runtime.h>
#include <math.h>

#define FS_   44100.0
#define B_    8
#define T_    22050
#define NCH   31
#define LG    2048
#define LH    512
#define MM    12
#define BN    248          // B_*NCH

#define H1LEN 1023         // LH+LH-1
#define H1PAD 1024         // padded to 1024 taps, tap 1023 == 0 (bit-identical)

#define C2T   512          // t-tile for conv2/ihc
#define C2THR 128          // threads (each does 4 consecutive t)

#define IHCK  128          // IHC FIR taps

#define MODL  441
#define MODC  50           // MODL*MODC == T_
#define MCT   63           // modC tile width (441 = 7*63)

#define NBLK  62           // k_scan blocks: 4 seqs per wave
#define TQ    5520         // env time-quads per seq (22080/4, padded)
#define ADP   22052        // ad row pitch (multiple of 4 floats -> 16B rows)

// ---- workspace layout (in floats) ----
#define OFF_H1    0                       // 1024
#define OFF_G5    1024                    // 256
#define OFF_X1    1280                    // 176400 (pad to 177696)
#define OFF_HW    177696                  // hw: BN*T_ = 5468400 ; ad alias: BN*ADP = 5468896
#define OFF_AD    OFF_HW
#define OFF_ENV   (OFF_HW + 5468896)      // 5646592 ; env interleaved: NBLK*TQ*16 = 5475840
#define OFF_SEND  (OFF_ENV + 5475840)     // 11122432 ; 297600
#define OFF_SINIT (OFF_SEND + 297600)     // 11420032 ; 297600 ; total 11717632 fl = 46.9 MB

struct ScanP {
  float a1[5], b0[5], factor[5], efl2[5], offset[5], init[5], rinit[5];
  float minlvl, corr, scale;
};
struct ModP {
  float pre[12], pim[12], pb0[12], pLre[12], pLim[12];
  float att;
};

typedef float f32x4_t __attribute__((ext_vector_type(4)));

// ---------- combined hp*me FIR (length 1023, padded to 1024 with a zero tap) ----------
__global__ void k_h1(const float* __restrict__ hp, const float* __restrict__ me,
                     float* __restrict__ h1) {
  int k = blockIdx.x * blockDim.x + threadIdx.x;
  if (k >= H1PAD) return;
  int j0 = max(0, k - (LH - 1));
  int j1 = min(LH - 1, k);
  float acc = 0.f;
  for (int j = j0; j <= j1; ++j) acc += hp[j] * me[k - j];  // k=1023: j0>j1 -> 0
  h1[k] = acc;
}

// ---------- IHC LP^5 impulse response: (1-a)^5 * C(k+4,4) * a^k ----------
__global__ void k_g5(float l2a, float c5, float* __restrict__ g5) {
  int k = threadIdx.x;  // 128
  float kf = (float)k;
  float binom = (kf + 1.f) * (kf + 2.f) * (kf + 3.f) * (kf + 4.f) * (1.0f / 24.0f);
  g5[k] = c5 * binom * exp2f(kf * l2a);
}

// ---------- conv1: x (*) h1 -> x1,  K=1024 (tap 1023 = 0), 1 output/thread ----------
// Filter taps wave-uniform -> ONE float4 VMEM load per 4 taps (was 4 scalar
// VMEM loads; uniform scalar loads do NOT auto-scalarize to s_load -> TA-bound).
__global__ void k_conv1(const float* __restrict__ x, const float* __restrict__ h1,
                        float* __restrict__ x1) {
  __shared__ float xs[256 + 1023];  // 1279
  int b = blockIdx.y;
  int t0 = blockIdx.x * 256;
  const float* xb = x + b * T_;
  for (int i = threadIdx.x; i < 1279; i += 256) {
    int g = t0 - 1023 + i;
    xs[i] = (g >= 0 && g < T_) ? xb[g] : 0.f;
  }
  __syncthreads();
  int t = t0 + threadIdx.x;
  if (t >= T_) return;
  float acc = 0.f;
  for (int k4 = 0; k4 < H1PAD / 4; ++k4) {
    int k = k4 * 4;
    float4 hh = *(const float4*)&h1[k];
    acc = fmaf(hh.x, xs[threadIdx.x + 1023 - k],     acc);
    acc = fmaf(hh.y, xs[threadIdx.x + 1023 - k - 1], acc);
    acc = fmaf(hh.z, xs[threadIdx.x + 1023 - k - 2], acc);
    acc = fmaf(hh.w, xs[threadIdx.x + 1023 - k - 3], acc);  // k=1023: hh.w==0
  }
  x1[b * T_ + t] = acc;
}

// ---------- conv2: x1 (*) gt[n] -> hw = relu(y), K=2048, 4 outputs/thread ----------
// Filter taps wave-uniform -> ONE float4 VMEM load per iteration (1 instr for
// 16 FMAs; was 4 scalar VMEM loads -> TA-issue-bound at ~360us/kernel).
__global__ __launch_bounds__(C2THR) void k_conv2(const float* __restrict__ x1,
                                                 const float* __restrict__ gt,
                                                 float* __restrict__ hw) {
  const int H = LG - 1;  // 2047
  __shared__ __align__(16) float xs[C2T + LG];  // 2560
  int n = blockIdx.y % NCH, b = blockIdx.y / NCH;
  int t0 = blockIdx.x * C2T;
  const float* xb = x1 + b * T_;
  for (int i = threadIdx.x; i < C2T + LG; i += C2THR) {
    int g = t0 - H + i;
    xs[i] = (g >= 0 && g < T_) ? xb[g] : 0.f;
  }
  __syncthreads();
  const float* gtn = gt + n * LG;
  int base = threadIdx.x * 4;
  float a0 = 0.f, a1 = 0.f, a2 = 0.f, a3 = 0.f;
  float4 hi = *(const float4*)&xs[base + H + 1];  // [base+H+1 .. base+H+4]
  for (int k4 = 0; k4 < LG / 4; ++k4) {
    int k = k4 * 4;
    float4 lo = *(const float4*)&xs[base + H - 3 - k];  // [base+H-3-k .. base+H-k]
    float4 hh = *(const float4*)&gtn[k];
    a0 = fmaf(hh.x, lo.w, a0); a1 = fmaf(hh.x, hi.x, a1); a2 = fmaf(hh.x, hi.y, a2); a3 = fmaf(hh.x, hi.z, a3);
    a0 = fmaf(hh.y, lo.z, a0); a1 = fmaf(hh.y, lo.w, a1); a2 = fmaf(hh.y, hi.x, a2); a3 = fmaf(hh.y, hi.y, a3);
    a0 = fmaf(hh.z, lo.y, a0); a1 = fmaf(hh.z, lo.z, a1); a2 = fmaf(hh.z, lo.w, a2); a3 = fmaf(hh.z, hi.x, a3);
    a0 = fmaf(hh.w, lo.x, a0); a1 = fmaf(hh.w, lo.y, a1); a2 = fmaf(hh.w, lo.z, a2); a3 = fmaf(hh.w, lo.w, a3);
    hi = lo;
  }
  float* o = hw + (size_t)(b * NCH + n) * T_;
  int t = t0 + base;
  if (t + 0 < T_) o[t + 0] = fmaxf(a0, 0.f);
  if (t + 1 < T_) o[t + 1] = fmaxf(a1, 0.f);
  if (t + 2 < T_) o[t + 2] = fmaxf(a2, 0.f);
  if (t + 3 < T_) o[t + 3] = fmaxf(a3, 0.f);
}

// ---------- IHC FIR: hw (*) g5 -> env (interleaved), K=128, 4 outputs/thread ----------
// env layout: [blk=bn/4][tq=t/4][s=bn%4][tt=t%4]  (one float4 store per thread)
// g5 taps wave-uniform -> ONE float4 VMEM load per iteration.
__global__ __launch_bounds__(C2THR) void k_ihc(const float* __restrict__ hw,
                                               const float* __restrict__ g5,
                                               float* __restrict__ env) {
  const int H = IHCK - 1;  // 127
  __shared__ __align__(16) float xs[C2T + IHCK];  // 640
  int bn = blockIdx.y;
  int t0 = blockIdx.x * C2T;
  const float* xb = hw + (size_t)bn * T_;
  for (int i = threadIdx.x; i < C2T + IHCK; i += C2THR) {
    int g = t0 - H + i;
    xs[i] = (g >= 0 && g < T_) ? xb[g] : 0.f;
  }
  __syncthreads();
  int base = threadIdx.x * 4;
  float a0 = 0.f, a1 = 0.f, a2 = 0.f, a3 = 0.f;
  float4 hi = *(const float4*)&xs[base + H + 1];
  for (int k4 = 0; k4 < IHCK / 4; ++k4) {
    int k = k4 * 4;
    float4 lo = *(const float4*)&xs[base + H - 3 - k];
    float4 hh = *(const float4*)&g5[k];
    a0 = fmaf(hh.x, lo.w, a0); a1 = fmaf(hh.x, hi.x, a1); a2 = fmaf(hh.x, hi.y, a2); a3 = fmaf(hh.x, hi.z, a3);
    a0 = fmaf(hh.y, lo.z, a0); a1 = fmaf(hh.y, lo.w, a1); a2 = fmaf(hh.y, hi.x, a2); a3 = fmaf(hh.y, hi.y, a3);
    a0 = fmaf(hh.z, lo.y, a0); a1 = fmaf(hh.z, lo.z, a1); a2 = fmaf(hh.z, lo.w, a2); a3 = fmaf(hh.z, hi.x, a3);
    a0 = fmaf(hh.w, lo.x, a0); a1 = fmaf(hh.w, lo.y, a1); a2 = fmaf(hh.w, lo.z, a2); a3 = fmaf(hh.w, lo.w, a3);
    hi = lo;
  }
  int t = t0 + base;
  if (t < T_) {  // last quad may carry 2 junk lanes (t=22050/22051) -> never affect stored outputs
    int blk = bn >> 2, s = bn & 3, tq = t >> 2;
    float4* o4 = (float4*)(env + ((size_t)(blk * TQ + tq) * 4 + s) * 4);
    *o4 = make_float4(a0, a1, a2, a3);
  }
}

// ---------- adaptation loops: systolic 5-lane pipeline, 1 seq per 16-lane row ----------
// Lane q (=lane&15) = stage j for q<5; q>=5 idle. Stage j at group k processes t=k-j.
// tmp passes j-1 -> j via DPP row_shr:1; lane q=0 (stage 0) gets `old` = env value
// (bound_ctrl=false) -- no select on the recurrence chain.
//
// Memory pipeline: opaque inline-asm global_load_dwordx4 into an 8-deep
// statically-named register queue (the compiler collapses C-level prefetch),
// counted s_waitcnt vmcnt(14) (load consumed now was issued 8 substeps ago;
// 7 loads + 7 stores after it in the VMEM FIFO). Prologue drains vmcnt(0) once.
// sched_barrier(0) after each wait keeps hipcc from hoisting register-only
// consumers past the inline-asm wait.  [EXACT R2 kernel: measured 810us, passed.]
#define GLD0(DST, PTR)  asm volatile("global_load_dwordx4 %0, %1, off"            : "=v"(DST) : "v"(PTR) : "memory")
#define GLD(DST, PTR, OFFB) \
  asm volatile("global_load_dwordx4 %0, %1, off offset:" #OFFB : "=v"(DST) : "v"(PTR) : "memory")
#define VMWAIT(N) do { asm volatile("s_waitcnt vmcnt(" #N ")" ::: "memory"); \
                       __builtin_amdgcn_sched_barrier(0); } while (0)

__global__ __launch_bounds__(64, 1) void k_scan(const float* __restrict__ env,
                                                float* __restrict__ ad, ScanP p) {
  const int lane = threadIdx.x;
  const int row = lane >> 4, q = lane & 15;
  const int seq = blockIdx.x * 4 + row;
  const bool is4 = (q == 4);
  const float* eb = env + (size_t)blockIdx.x * TQ * 16 + row * 4;  // +tq*16 per quad
  float* o = ad + (size_t)seq * ADP;

#define SEL5(A) (q==0 ? (A)[0] : q==1 ? (A)[1] : q==2 ? (A)[2] : q==3 ? (A)[3] : (A)[4])
  const float A1  = SEL5(p.a1),   B0  = SEL5(p.b0), FAC = SEL5(p.factor);
  const float EF  = SEL5(p.efl2), NEF = -EF,        NOFF = -SEL5(p.offset);
  float st = SEL5(p.init);
  float r  = SEL5(p.rinit);
#undef SEL5
  const float SC = p.scale, NCS = -p.corr * p.scale, ML = p.minlvl;

  float a1st = A1 * st;   // off-critical-path precompute of a1*st for the state fma
  float tmp = 0.f;
  float o0 = 0.f, o1 = 0.f, o2 = 0.f, o3 = 0.f;

  // tmp = min(v, lim) is exact away from v==1 (lim(v)=1+m*tanh((v-1)/m) crosses
  // v only there; ~1 ulp at crossover, same tolerance class as rcp divide).
#define BODY(EV)                                                              \
    float evc = fmaxf((EV), ML);                                              \
    float tin = __int_as_float(__builtin_amdgcn_update_dpp(                   \
        __float_as_int(evc), __float_as_int(tmp), 0x111, 0xF, 0xF, false));   \
    float v   = tin * r;                                                      \
    float ex  = __builtin_amdgcn_exp2f(fmaf(EF, v, NEF));                     \
    float lim = fmaf(FAC, __builtin_amdgcn_rcpf(1.0f + ex), NOFF);            \
    tmp = fminf(v, lim);

#define STEP_FILL(EV, K)                                                      \
  { BODY(EV)                                                                  \
    float nst = fmaf(B0, tmp, a1st);                                          \
    st = ((K) >= q) ? nst : st;                                               \
    a1st = A1 * st;                                                           \
    r  = __builtin_amdgcn_rcpf(st); }

#define STEP(EV, OSLOT)                                                       \
  { BODY(EV)                                                                  \
    st = fmaf(B0, tmp, a1st);                                                 \
    a1st = A1 * st;                                                           \
    r  = __builtin_amdgcn_rcpf(st);                                           \
    OSLOT = fmaf(tmp, SC, NCS); }

  // 8-deep opaque prefetch queue + fill quad
  f32x4_t bF, b0, b1, b2, b3, b4, b5, b6, b7;
  GLD0(bF, eb);
  GLD(b0, eb, 64);   GLD(b1, eb, 128);  GLD(b2, eb, 192);  GLD(b3, eb, 256);
  GLD(b4, eb, 320);  GLD(b5, eb, 384);  GLD(b6, eb, 448);  GLD(b7, eb, 512);
  VMWAIT(0);

  // pipeline fill: groups 0..3 (stage-4 t < 0, no stores), quad 0
  STEP_FILL(bF.x, 0) STEP_FILL(bF.y, 1) STEP_FILL(bF.z, 2) STEP_FILL(bF.w, 3)

  const float* pld = eb + 9 * 16;  // next quad to load (quad 9)
  float* po = o;                   // next store base (t = 32*j)

#define SUBSTEP(BUF, FOFF, BOFF)                                              \
    VMWAIT(14);                                                               \
    STEP(BUF.x, o0) STEP(BUF.y, o1) STEP(BUF.z, o2) STEP(BUF.w, o3)           \
    if (is4) *(float4*)(po + FOFF) = make_float4(o0, o1, o2, o3);             \
    GLD(BUF, pld, BOFF);

  // main: 689 iterations x 8 quads = quads 1..5512, groups 4..22051 -> t=0..22047.
  // Refills run to quad 5520 (64B past this row's TQ=5520 region -> lands in the
  // next block's region / OFF_SEND scratch: allocated, dead data).
  for (int j = 0; j < 689; ++j) {
    SUBSTEP(b0,  0,   0)
    SUBSTEP(b1,  4,  64)
    SUBSTEP(b2,  8, 128)
    SUBSTEP(b3, 12, 192)
    SUBSTEP(b4, 16, 256)
    SUBSTEP(b5, 20, 320)
    SUBSTEP(b6, 24, 384)
    SUBSTEP(b7, 28, 448)
    pld += 8 * 16;
    po  += 32;
  }
#undef SUBSTEP

  // drain: groups 22052, 22053 -> t = 22048, 22049 (+2 pad floats, row pitch 22052)
  STEP(0.f, o0) STEP(0.f, o1)
  if (is4) *(float4*)(o + 22048) = make_float4(o0, o1, o2, o3);
#undef STEP
#undef STEP_FILL
#undef BODY
}

// ---------- modulation filterbank, chunk-parallel linear scan ----------
__global__ void k_modA(const float* __restrict__ ad, float2* __restrict__ send, ModP mp) {
  int id = blockIdx.x * 256 + threadIdx.x;
  if (id >= MODC * BN * MM) return;
  int m = id % MM, bn = (id / MM) % BN, c = id / (MM * BN);
  const float* a = ad + (size_t)bn * ADP + c * MODL;
  float pre = mp.pre[m], pim = mp.pim[m], b0 = mp.pb0[m];
  float sre = 0.f, sim = 0.f;
  for (int i = 0; i < MODL; ++i) {
    float xv = a[i];
    float nre = fmaf(pre, sre, fmaf(-pim, sim, b0 * xv));
    sim = fmaf(pre, sim, pim * sre);
    sre = nre;
  }
  send[id] = make_float2(sre, sim);
}

__global__ void k_modB(const float2* __restrict__ send, float2* __restrict__ sinit, ModP mp) {
  int id = blockIdx.x * blockDim.x + threadIdx.x;
  if (id >= BN * MM) return;
  int m = id % MM;
  float pLre = mp.pLre[m], pLim = mp.pLim[m];
  float Sre = 0.f, Sim = 0.f;
  for (int c = 0; c < MODC; ++c) {
    int idx = c * BN * MM + id;
    sinit[idx] = make_float2(Sre, Sim);
    float2 se = send[idx];
    float nre = pLre * Sre - pLim * Sim + se.x;
    Sim = pLre * Sim + pLim * Sre + se.y;
    Sre = nre;
  }
}

// ---------- modC: recurrence + COALESCED writes via LDS transpose ----------
// Block = 256 consecutive (bn,m) rows at fixed c; 7 tiles of 63 outputs buffered
// in LDS [256][63], waves write back rows with lanes at consecutive addresses.
__global__ __launch_bounds__(256) void k_modC(const float* __restrict__ ad,
                                              const float2* __restrict__ sinit,
                                              float* __restrict__ out, ModP mp) {
  __shared__ float tile[256][MCT];  // 63 KB
  const int tid = threadIdx.x;
  const int c = blockIdx.y;
  const int idc = blockIdx.x * 256 + tid;      // bn*MM + m
  const bool act = idc < BN * MM;
  const int idcc = act ? idc : 0;
  const int m = idcc % MM, bn = idcc / MM;
  const float* a = ad + (size_t)bn * ADP + c * MODL;
  float2 s0 = sinit[c * BN * MM + idcc];
  float sre = s0.x, sim = s0.y;
  const float pre = mp.pre[m], pim = mp.pim[m], b0 = mp.pb0[m], att = mp.att;
  const bool low = (m < 3);  // mfc <= 10 Hz
  const int wv = tid >> 6, ln = tid & 63;
  for (int tb = 0; tb < 7; ++tb) {
    for (int i = 0; i < MCT; ++i) {
      float xv = a[tb * MCT + i];
      float nre = fmaf(pre, sre, fmaf(-pim, sim, b0 * xv));
      sim = fmaf(pre, sim, pim * sre);
      sre = nre;
      float mag = att * sqrtf(fmaf(sre, sre, fmaf(sim, sim, 1e-12f)));
      tile[tid][i] = low ? sre : mag;
    }
    __syncthreads();
    if (ln < MCT) {
      for (int rr = 0; rr < 64; ++rr) {
        int rowi = (wv << 6) + rr;
        int gid = blockIdx.x * 256 + rowi;
        if (gid < BN * MM)
          out[(size_t)gid * T_ + c * MODL + tb * MCT + ln] = tile[rowi][ln];
      }
    }
    __syncthreads();
  }
}

extern "C" void kernel_launch(void* const* d_in, const int* in_sizes, int n_in,
                              void* d_out, int out_size, void* d_ws, size_t ws_size,
                              hipStream_t stream) {
  const float* x  = (const float*)d_in[0];
  const float* hp = (const float*)d_in[1];
  const float* me = (const float*)d_in[2];
  const float* gt = (const float*)d_in[3];
  float* ws  = (float*)d_ws;
  float* out = (float*)d_out;

  // ---- host-side constant computation (double precision) ----
  ScanP sp;
  const double taus[5] = {0.005, 0.05, 0.129, 0.253, 0.5};
  for (int j = 0; j < 5; ++j) {
    double a1 = exp(-1.0 / (FS_ * taus[j]));
    double init = pow(1e-5, pow(2.0, -(double)(j + 1)));
    double maxv = (1.0 - init * init) * 5.0 - 1.0;
    sp.a1[j] = (float)a1;
    sp.b0[j] = (float)(1.0 - a1);
    sp.factor[j] = (float)(2.0 * maxv);
    sp.efl2[j] = (float)(-2.0 / maxv * 1.4426950408889634);  // expfac * log2(e)
    sp.offset[j] = (float)(maxv - 1.0);
    sp.init[j] = (float)init;
    sp.rinit[j] = (float)(1.0 / init);
  }
  sp.minlvl = 1e-5f;
  double corr = pow(1e-5, pow(2.0, -5.0));
  sp.corr = (float)corr;
  sp.scale = (float)(100.0 / (1.0 - corr));

  ModP mp;
  const double mfc[12] = {2.5, 5.0, 10.0, 16.7, 27.8, 46.3, 77.2, 128.6, 214.3, 357.2, 595.4, 992.3};
  for (int m = 0; m < 12; ++m) {
    double r = exp(-M_PI * (mfc[m] / 2.0) / FS_);
    double th = 2.0 * M_PI * mfc[m] / FS_;
    mp.pre[m] = (float)(r * cos(th));
    mp.pim[m] = (float)(r * sin(th));
    mp.pb0[m] = (float)(1.0 - r);
    double rL = pow(r, (double)MODL);
    mp.pLre[m] = (float)(rL * cos((double)MODL * th));
    mp.pLim[m] = (float)(rL * sin((double)MODL * th));
  }
  mp.att = (float)(1.0 / sqrt(2.0));

  double alp = exp(-2.0 * M_PI * 2000.0 / FS_);
  float l2a = (float)(log(alp) * 1.4426950408889634);
  float c5  = (float)pow(1.0 - alp, 5.0);

  float* h1  = ws + OFF_H1;
  float* g5  = ws + OFF_G5;
  float* x1  = ws + OFF_X1;
  float* hw  = ws + OFF_HW;
  float* env = ws + OFF_ENV;
  float* ad  = ws + OFF_AD;  // aliases hw (dead after IHC)
  float2* send  = (float2*)(ws + OFF_SEND);
  float2* sinit = (float2*)(ws + OFF_SINIT);

  k_h1<<<dim3(2), dim3(512), 0, stream>>>(hp, me, h1);
  k_g5<<<dim3(1), dim3(128), 0, stream>>>(l2a, c5, g5);
  k_conv1<<<dim3(87, B_), dim3(256), 0, stream>>>(x, h1, x1);
  k_conv2<<<dim3((T_ + C2T - 1) / C2T, BN), dim3(C2THR), 0, stream>>>(x1, gt, hw);
  k_ihc<<<dim3((T_ + C2T - 1) / C2T, BN), dim3(C2THR), 0, stream>>>(hw, g5, env);
  k_scan<<<dim3(NBLK), dim3(64), 0, stream>>>(env, ad, sp);  // 4 seqs/wave, 5-lane systolic
  int nmod = MODC * BN * MM;
  k_modA<<<dim3((nmod + 255) / 256), dim3(256), 0, stream>>>(ad, send, mp);
  k_modB<<<dim3((BN * MM + 255) / 256), dim3(256), 0, stream>>>(send, sinit, mp);
  k_modC<<<dim3((BN * MM + 255) / 256, MODC), dim3(256), 0, stream>>>(ad, sinit, out, mp);
}

// Round 8
// 1566.064 us; speedup vs baseline: 1.2194x; 1.0755x over previous
//
#include <hip/hip_runtime.h>
#include <math.h>

#define FS_   44100.0
#define B_    8
#define T_    22050
#define NCH   31
#define LG    2048
#define LH    512
#define MM    12
#define BN    248          // B_*NCH

#define H1LEN 1023         // LH+LH-1
#define H1PAD 1024         // padded to 1024 taps, tap 1023 == 0 (bit-identical)

#define C2T   512          // t-tile for conv2/ihc
#define C2THR 128          // threads (each does 4 consecutive t)

#define IHCK  128          // IHC FIR taps

#define MODL  441
#define MODC  50           // MODL*MODC == T_
#define MCT   63           // modC tile width (441 = 7*63)

#define NBLK  62           // k_scan blocks: 4 seqs per wave
#define TQ    5520         // env time-quads per seq (22080/4, padded)
#define ADP   22052        // ad row pitch (multiple of 4 floats -> 16B rows)

// ---- workspace layout (in floats) ----
#define OFF_H1    0                       // 1024
#define OFF_G5    1024                    // 128
#define OFF_KEFF  1152                    // 31 (within the 256-float G5 slot)
#define OFF_X1    1280                    // 176400 (pad to 177696)
#define OFF_HW    177696                  // hw: BN*T_ = 5468400 ; ad alias: BN*ADP = 5468896
#define OFF_AD    OFF_HW
#define OFF_ENV   (OFF_HW + 5468896)      // 5646592 ; env interleaved: NBLK*TQ*16 = 5475840
#define OFF_SEND  (OFF_ENV + 5475840)     // 11122432 ; 297600
#define OFF_SINIT (OFF_SEND + 297600)     // 11420032 ; 297600 ; total 11717632 fl = 46.9 MB

struct ScanP {
  float a1[5], b0[5], factor[5], efl2[5], offset[5], init[5], rinit[5];
  float minlvl, corr, scale;
};
struct ModP {
  float pre[12], pim[12], pb0[12], pLre[12], pLim[12];
  float att;
};

typedef float f32x4_t __attribute__((ext_vector_type(4)));

// ---------- combined hp*me FIR (length 1023, padded to 1024 with a zero tap) ----------
__global__ void k_h1(const float* __restrict__ hp, const float* __restrict__ me,
                     float* __restrict__ h1) {
  int k = blockIdx.x * blockDim.x + threadIdx.x;
  if (k >= H1PAD) return;
  int j0 = max(0, k - (LH - 1));
  int j1 = min(LH - 1, k);
  float acc = 0.f;
  for (int j = j0; j <= j1; ++j) acc += hp[j] * me[k - j];  // k=1023: j0>j1 -> 0
  h1[k] = acc;
}

// ---------- IHC LP^5 impulse response: (1-a)^5 * C(k+4,4) * a^k ----------
__global__ void k_g5(float l2a, float c5, float* __restrict__ g5) {
  int k = threadIdx.x;  // 128
  float kf = (float)k;
  float binom = (kf + 1.f) * (kf + 2.f) * (kf + 3.f) * (kf + 4.f) * (1.0f / 24.0f);
  g5[k] = c5 * binom * exp2f(kf * l2a);
}

// ---------- per-channel effective gammatone length ----------
// Gammatone t^3 exp(-2pi bw t) envelopes die long before 2048 taps for high-fc
// channels (t_eff = 3.49/bw at 1e-6 of peak: fc=8k -> ~170 taps; avg ~1050).
// Keff[n] = last tap >= 1e-6*peak, rounded up to x4. Tail contribution to hw
// < ~1e-4 relative, further crushed by the compressive adaptation loops.
__global__ void k_keff(const float* __restrict__ gt, float* __restrict__ keff) {
  __shared__ float red[256];
  int n = blockIdx.x, tid = threadIdx.x;
  const float* h = gt + n * LG;
  float mx = 0.f;
  for (int k = tid; k < LG; k += 256) mx = fmaxf(mx, fabsf(h[k]));
  red[tid] = mx; __syncthreads();
  for (int s = 128; s > 0; s >>= 1) {
    if (tid < s) red[tid] = fmaxf(red[tid], red[tid + s]);
    __syncthreads();
  }
  float eps = 1e-6f * red[0];
  __syncthreads();
  int hi = 0;
  for (int k = tid; k < LG; k += 256) if (fabsf(h[k]) >= eps) hi = k;
  red[tid] = (float)hi; __syncthreads();
  for (int s = 128; s > 0; s >>= 1) {
    if (tid < s) red[tid] = fmaxf(red[tid], red[tid + s]);
    __syncthreads();
  }
  if (tid == 0) {
    int kk = (int)red[0] + 1;
    kk = (kk + 3) & ~3;
    if (kk < 8) kk = 8;
    if (kk > LG) kk = LG;
    keff[n] = (float)kk;
  }
}

// ---------- conv1: x (*) h1 -> x1,  K=1024 (tap 1023 = 0), 1 output/thread ----------
__global__ void k_conv1(const float* __restrict__ x, const float* __restrict__ h1,
                        float* __restrict__ x1) {
  __shared__ float xs[256 + 1023];  // 1279
  int b = blockIdx.y;
  int t0 = blockIdx.x * 256;
  const float* xb = x + b * T_;
  for (int i = threadIdx.x; i < 1279; i += 256) {
    int g = t0 - 1023 + i;
    xs[i] = (g >= 0 && g < T_) ? xb[g] : 0.f;
  }
  __syncthreads();
  int t = t0 + threadIdx.x;
  if (t >= T_) return;
  float acc = 0.f;
  for (int k4 = 0; k4 < H1PAD / 4; ++k4) {
    int k = k4 * 4;
    float4 hh = *(const float4*)&h1[k];
    acc = fmaf(hh.x, xs[threadIdx.x + 1023 - k],     acc);
    acc = fmaf(hh.y, xs[threadIdx.x + 1023 - k - 1], acc);
    acc = fmaf(hh.z, xs[threadIdx.x + 1023 - k - 2], acc);
    acc = fmaf(hh.w, xs[threadIdx.x + 1023 - k - 3], acc);  // k=1023: hh.w==0
  }
  x1[b * T_ + t] = acc;
}

// ---------- conv2: x1 (*) gt[n] -> hw = relu(y), K=Keff[n] (<=2048), 4 outs/thread ----------
// K-loop and staging range bounded by the block-uniform per-channel Keff.
__global__ __launch_bounds__(C2THR) void k_conv2(const float* __restrict__ x1,
                                                 const float* __restrict__ gt,
                                                 const float* __restrict__ keff,
                                                 float* __restrict__ hw) {
  const int H = LG - 1;  // 2047
  __shared__ __align__(16) float xs[C2T + LG];  // 2560
  int n = blockIdx.y % NCH, b = blockIdx.y / NCH;
  int t0 = blockIdx.x * C2T;
  const int KK = (int)keff[n];                      // uniform, multiple of 4
  const int IMIN = max(0, (H - KK - 3) & ~3);       // lowest xs index ever read
  const float* xb = x1 + b * T_;
  for (int i = IMIN + threadIdx.x; i < C2T + LG; i += C2THR) {
    int g = t0 - H + i;
    xs[i] = (g >= 0 && g < T_) ? xb[g] : 0.f;
  }
  __syncthreads();
  const float* gtn = gt + n * LG;
  int base = threadIdx.x * 4;
  float a0 = 0.f, a1 = 0.f, a2 = 0.f, a3 = 0.f;
  float4 hi = *(const float4*)&xs[base + H + 1];  // [base+H+1 .. base+H+4]
  for (int k4 = 0; k4 < (KK >> 2); ++k4) {
    int k = k4 * 4;
    float4 lo = *(const float4*)&xs[base + H - 3 - k];  // [base+H-3-k .. base+H-k]
    float4 hh = *(const float4*)&gtn[k];
    a0 = fmaf(hh.x, lo.w, a0); a1 = fmaf(hh.x, hi.x, a1); a2 = fmaf(hh.x, hi.y, a2); a3 = fmaf(hh.x, hi.z, a3);
    a0 = fmaf(hh.y, lo.z, a0); a1 = fmaf(hh.y, lo.w, a1); a2 = fmaf(hh.y, hi.x, a2); a3 = fmaf(hh.y, hi.y, a3);
    a0 = fmaf(hh.z, lo.y, a0); a1 = fmaf(hh.z, lo.z, a1); a2 = fmaf(hh.z, lo.w, a2); a3 = fmaf(hh.z, hi.x, a3);
    a0 = fmaf(hh.w, lo.x, a0); a1 = fmaf(hh.w, lo.y, a1); a2 = fmaf(hh.w, lo.z, a2); a3 = fmaf(hh.w, lo.w, a3);
    hi = lo;
  }
  float* o = hw + (size_t)(b * NCH + n) * T_;
  int t = t0 + base;
  if (t + 0 < T_) o[t + 0] = fmaxf(a0, 0.f);
  if (t + 1 < T_) o[t + 1] = fmaxf(a1, 0.f);
  if (t + 2 < T_) o[t + 2] = fmaxf(a2, 0.f);
  if (t + 3 < T_) o[t + 3] = fmaxf(a3, 0.f);
}

// ---------- IHC FIR: hw (*) g5 -> env (interleaved), K=128, 4 outputs/thread ----------
// env layout: [blk=bn/4][tq=t/4][s=bn%4][tt=t%4]  (one float4 store per thread)
__global__ __launch_bounds__(C2THR) void k_ihc(const float* __restrict__ hw,
                                               const float* __restrict__ g5,
                                               float* __restrict__ env) {
  const int H = IHCK - 1;  // 127
  __shared__ __align__(16) float xs[C2T + IHCK];  // 640
  int bn = blockIdx.y;
  int t0 = blockIdx.x * C2T;
  const float* xb = hw + (size_t)bn * T_;
  for (int i = threadIdx.x; i < C2T + IHCK; i += C2THR) {
    int g = t0 - H + i;
    xs[i] = (g >= 0 && g < T_) ? xb[g] : 0.f;
  }
  __syncthreads();
  int base = threadIdx.x * 4;
  float a0 = 0.f, a1 = 0.f, a2 = 0.f, a3 = 0.f;
  float4 hi = *(const float4*)&xs[base + H + 1];
  for (int k4 = 0; k4 < IHCK / 4; ++k4) {
    int k = k4 * 4;
    float4 lo = *(const float4*)&xs[base + H - 3 - k];
    float4 hh = *(const float4*)&g5[k];
    a0 = fmaf(hh.x, lo.w, a0); a1 = fmaf(hh.x, hi.x, a1); a2 = fmaf(hh.x, hi.y, a2); a3 = fmaf(hh.x, hi.z, a3);
    a0 = fmaf(hh.y, lo.z, a0); a1 = fmaf(hh.y, lo.w, a1); a2 = fmaf(hh.y, hi.x, a2); a3 = fmaf(hh.y, hi.y, a3);
    a0 = fmaf(hh.z, lo.y, a0); a1 = fmaf(hh.z, lo.z, a1); a2 = fmaf(hh.z, lo.w, a2); a3 = fmaf(hh.z, hi.x, a3);
    a0 = fmaf(hh.w, lo.x, a0); a1 = fmaf(hh.w, lo.y, a1); a2 = fmaf(hh.w, lo.z, a2); a3 = fmaf(hh.w, lo.w, a3);
    hi = lo;
  }
  int t = t0 + base;
  if (t < T_) {  // last quad may carry 2 junk lanes (t=22050/22051) -> never affect stored outputs
    int blk = bn >> 2, s = bn & 3, tq = t >> 2;
    float4* o4 = (float4*)(env + ((size_t)(blk * TQ + tq) * 4 + s) * 4);
    *o4 = make_float4(a0, a1, a2, a3);
  }
}

// ---------- adaptation loops: systolic 5-lane pipeline, 1 seq per 16-lane row ----------
// [EXACT R2 kernel: measured 807-812us, passed. See prior rounds for derivation.]
#define GLD0(DST, PTR)  asm volatile("global_load_dwordx4 %0, %1, off"            : "=v"(DST) : "v"(PTR) : "memory")
#define GLD(DST, PTR, OFFB) \
  asm volatile("global_load_dwordx4 %0, %1, off offset:" #OFFB : "=v"(DST) : "v"(PTR) : "memory")
#define VMWAIT(N) do { asm volatile("s_waitcnt vmcnt(" #N ")" ::: "memory"); \
                       __builtin_amdgcn_sched_barrier(0); } while (0)

__global__ __launch_bounds__(64, 1) void k_scan(const float* __restrict__ env,
                                                float* __restrict__ ad, ScanP p) {
  const int lane = threadIdx.x;
  const int row = lane >> 4, q = lane & 15;
  const int seq = blockIdx.x * 4 + row;
  const bool is4 = (q == 4);
  const float* eb = env + (size_t)blockIdx.x * TQ * 16 + row * 4;  // +tq*16 per quad
  float* o = ad + (size_t)seq * ADP;

#define SEL5(A) (q==0 ? (A)[0] : q==1 ? (A)[1] : q==2 ? (A)[2] : q==3 ? (A)[3] : (A)[4])
  const float A1  = SEL5(p.a1),   B0  = SEL5(p.b0), FAC = SEL5(p.factor);
  const float EF  = SEL5(p.efl2), NEF = -EF,        NOFF = -SEL5(p.offset);
  float st = SEL5(p.init);
  float r  = SEL5(p.rinit);
#undef SEL5
  const float SC = p.scale, NCS = -p.corr * p.scale, ML = p.minlvl;

  float a1st = A1 * st;   // off-critical-path precompute of a1*st for the state fma
  float tmp = 0.f;
  float o0 = 0.f, o1 = 0.f, o2 = 0.f, o3 = 0.f;

  // tmp = min(v, lim) is exact away from v==1 (lim(v)=1+m*tanh((v-1)/m) crosses
  // v only there; ~1 ulp at crossover, same tolerance class as rcp divide).
#define BODY(EV)                                                              \
    float evc = fmaxf((EV), ML);                                              \
    float tin = __int_as_float(__builtin_amdgcn_update_dpp(                   \
        __float_as_int(evc), __float_as_int(tmp), 0x111, 0xF, 0xF, false));   \
    float v   = tin * r;                                                      \
    float ex  = __builtin_amdgcn_exp2f(fmaf(EF, v, NEF));                     \
    float lim = fmaf(FAC, __builtin_amdgcn_rcpf(1.0f + ex), NOFF);            \
    tmp = fminf(v, lim);

#define STEP_FILL(EV, K)                                                      \
  { BODY(EV)                                                                  \
    float nst = fmaf(B0, tmp, a1st);                                          \
    st = ((K) >= q) ? nst : st;                                               \
    a1st = A1 * st;                                                           \
    r  = __builtin_amdgcn_rcpf(st); }

#define STEP(EV, OSLOT)                                                       \
  { BODY(EV)                                                                  \
    st = fmaf(B0, tmp, a1st);                                                 \
    a1st = A1 * st;                                                           \
    r  = __builtin_amdgcn_rcpf(st);                                           \
    OSLOT = fmaf(tmp, SC, NCS); }

  // 8-deep opaque prefetch queue + fill quad
  f32x4_t bF, b0, b1, b2, b3, b4, b5, b6, b7;
  GLD0(bF, eb);
  GLD(b0, eb, 64);   GLD(b1, eb, 128);  GLD(b2, eb, 192);  GLD(b3, eb, 256);
  GLD(b4, eb, 320);  GLD(b5, eb, 384);  GLD(b6, eb, 448);  GLD(b7, eb, 512);
  VMWAIT(0);

  // pipeline fill: groups 0..3 (stage-4 t < 0, no stores), quad 0
  STEP_FILL(bF.x, 0) STEP_FILL(bF.y, 1) STEP_FILL(bF.z, 2) STEP_FILL(bF.w, 3)

  const float* pld = eb + 9 * 16;  // next quad to load (quad 9)
  float* po = o;                   // next store base (t = 32*j)

#define SUBSTEP(BUF, FOFF, BOFF)                                              \
    VMWAIT(14);                                                               \
    STEP(BUF.x, o0) STEP(BUF.y, o1) STEP(BUF.z, o2) STEP(BUF.w, o3)           \
    if (is4) *(float4*)(po + FOFF) = make_float4(o0, o1, o2, o3);             \
    GLD(BUF, pld, BOFF);

  // main: 689 iterations x 8 quads = quads 1..5512, groups 4..22051 -> t=0..22047.
  // Refills run to quad 5520 (64B past this row's TQ=5520 region -> lands in the
  // next block's region / OFF_SEND scratch: allocated, dead data).
  for (int j = 0; j < 689; ++j) {
    SUBSTEP(b0,  0,   0)
    SUBSTEP(b1,  4,  64)
    SUBSTEP(b2,  8, 128)
    SUBSTEP(b3, 12, 192)
    SUBSTEP(b4, 16, 256)
    SUBSTEP(b5, 20, 320)
    SUBSTEP(b6, 24, 384)
    SUBSTEP(b7, 28, 448)
    pld += 8 * 16;
    po  += 32;
  }
#undef SUBSTEP

  // drain: groups 22052, 22053 -> t = 22048, 22049 (+2 pad floats, row pitch 22052)
  STEP(0.f, o0) STEP(0.f, o1)
  if (is4) *(float4*)(o + 22048) = make_float4(o0, o1, o2, o3);
#undef STEP
#undef STEP_FILL
#undef BODY
}

// ---------- modulation filterbank, chunk-parallel linear scan ----------
__global__ void k_modA(const float* __restrict__ ad, float2* __restrict__ send, ModP mp) {
  int id = blockIdx.x * 256 + threadIdx.x;
  if (id >= MODC * BN * MM) return;
  int m = id % MM, bn = (id / MM) % BN, c = id / (MM * BN);
  const float* a = ad + (size_t)bn * ADP + c * MODL;
  float pre = mp.pre[m], pim = mp.pim[m], b0 = mp.pb0[m];
  float sre = 0.f, sim = 0.f;
  for (int i = 0; i < MODL; ++i) {
    float xv = a[i];
    float nre = fmaf(pre, sre, fmaf(-pim, sim, b0 * xv));
    sim = fmaf(pre, sim, pim * sre);
    sre = nre;
  }
  send[id] = make_float2(sre, sim);
}

__global__ void k_modB(const float2* __restrict__ send, float2* __restrict__ sinit, ModP mp) {
  int id = blockIdx.x * blockDim.x + threadIdx.x;
  if (id >= BN * MM) return;
  int m = id % MM;
  float pLre = mp.pLre[m], pLim = mp.pLim[m];
  float Sre = 0.f, Sim = 0.f;
  for (int c = 0; c < MODC; ++c) {
    int idx = c * BN * MM + id;
    sinit[idx] = make_float2(Sre, Sim);
    float2 se = send[idx];
    float nre = pLre * Sre - pLim * Sim + se.x;
    Sim = pLre * Sim + pLim * Sre + se.y;
    Sre = nre;
  }
}

// ---------- modC: recurrence + COALESCED writes via LDS transpose ----------
__global__ __launch_bounds__(256) void k_modC(const float* __restrict__ ad,
                                              const float2* __restrict__ sinit,
                                              float* __restrict__ out, ModP mp) {
  __shared__ float tile[256][MCT];  // 63 KB
  const int tid = threadIdx.x;
  const int c = blockIdx.y;
  const int idc = blockIdx.x * 256 + tid;      // bn*MM + m
  const bool act = idc < BN * MM;
  const int idcc = act ? idc : 0;
  const int m = idcc % MM, bn = idcc / MM;
  const float* a = ad + (size_t)bn * ADP + c * MODL;
  float2 s0 = sinit[c * BN * MM + idcc];
  float sre = s0.x, sim = s0.y;
  const float pre = mp.pre[m], pim = mp.pim[m], b0 = mp.pb0[m], att = mp.att;
  const bool low = (m < 3);  // mfc <= 10 Hz
  const int wv = tid >> 6, ln = tid & 63;
  for (int tb = 0; tb < 7; ++tb) {
    for (int i = 0; i < MCT; ++i) {
      float xv = a[tb * MCT + i];
      float nre = fmaf(pre, sre, fmaf(-pim, sim, b0 * xv));
      sim = fmaf(pre, sim, pim * sre);
      sre = nre;
      float mag = att * sqrtf(fmaf(sre, sre, fmaf(sim, sim, 1e-12f)));
      tile[tid][i] = low ? sre : mag;
    }
    __syncthreads();
    if (ln < MCT) {
      for (int rr = 0; rr < 64; ++rr) {
        int rowi = (wv << 6) + rr;
        int gid = blockIdx.x * 256 + rowi;
        if (gid < BN * MM)
          out[(size_t)gid * T_ + c * MODL + tb * MCT + ln] = tile[rowi][ln];
      }
    }
    __syncthreads();
  }
}

extern "C" void kernel_launch(void* const* d_in, const int* in_sizes, int n_in,
                              void* d_out, int out_size, void* d_ws, size_t ws_size,
                              hipStream_t stream) {
  const float* x  = (const float*)d_in[0];
  const float* hp = (const float*)d_in[1];
  const float* me = (const float*)d_in[2];
  const float* gt = (const float*)d_in[3];
  float* ws  = (float*)d_ws;
  float* out = (float*)d_out;

  // ---- host-side constant computation (double precision) ----
  ScanP sp;
  const double taus[5] = {0.005, 0.05, 0.129, 0.253, 0.5};
  for (int j = 0; j < 5; ++j) {
    double a1 = exp(-1.0 / (FS_ * taus[j]));
    double init = pow(1e-5, pow(2.0, -(double)(j + 1)));
    double maxv = (1.0 - init * init) * 5.0 - 1.0;
    sp.a1[j] = (float)a1;
    sp.b0[j] = (float)(1.0 - a1);
    sp.factor[j] = (float)(2.0 * maxv);
    sp.efl2[j] = (float)(-2.0 / maxv * 1.4426950408889634);  // expfac * log2(e)
    sp.offset[j] = (float)(maxv - 1.0);
    sp.init[j] = (float)init;
    sp.rinit[j] = (float)(1.0 / init);
  }
  sp.minlvl = 1e-5f;
  double corr = pow(1e-5, pow(2.0, -5.0));
  sp.corr = (float)corr;
  sp.scale = (float)(100.0 / (1.0 - corr));

  ModP mp;
  const double mfc[12] = {2.5, 5.0, 10.0, 16.7, 27.8, 46.3, 77.2, 128.6, 214.3, 357.2, 595.4, 992.3};
  for (int m = 0; m < 12; ++m) {
    double r = exp(-M_PI * (mfc[m] / 2.0) / FS_);
    double th = 2.0 * M_PI * mfc[m] / FS_;
    mp.pre[m] = (float)(r * cos(th));
    mp.pim[m] = (float)(r * sin(th));
    mp.pb0[m] = (float)(1.0 - r);
    double rL = pow(r, (double)MODL);
    mp.pLre[m] = (float)(rL * cos((double)MODL * th));
    mp.pLim[m] = (float)(rL * sin((double)MODL * th));
  }
  mp.att = (float)(1.0 / sqrt(2.0));

  double alp = exp(-2.0 * M_PI * 2000.0 / FS_);
  float l2a = (float)(log(alp) * 1.4426950408889634);
  float c5  = (float)pow(1.0 - alp, 5.0);

  float* h1   = ws + OFF_H1;
  float* g5   = ws + OFF_G5;
  float* keff = ws + OFF_KEFF;
  float* x1   = ws + OFF_X1;
  float* hw   = ws + OFF_HW;
  float* env  = ws + OFF_ENV;
  float* ad   = ws + OFF_AD;  // aliases hw (dead after IHC)
  float2* send  = (float2*)(ws + OFF_SEND);
  float2* sinit = (float2*)(ws + OFF_SINIT);

  k_h1<<<dim3(2), dim3(512), 0, stream>>>(hp, me, h1);
  k_g5<<<dim3(1), dim3(128), 0, stream>>>(l2a, c5, g5);
  k_keff<<<dim3(NCH), dim3(256), 0, stream>>>(gt, keff);
  k_conv1<<<dim3(87, B_), dim3(256), 0, stream>>>(x, h1, x1);
  k_conv2<<<dim3((T_ + C2T - 1) / C2T, BN), dim3(C2THR), 0, stream>>>(x1, gt, keff, hw);
  k_ihc<<<dim3((T_ + C2T - 1) / C2T, BN), dim3(C2THR), 0, stream>>>(hw, g5, env);
  k_scan<<<dim3(NBLK), dim3(64), 0, stream>>>(env, ad, sp);  // 4 seqs/wave, 5-lane systolic
  int nmod = MODC * BN * MM;
  k_modA<<<dim3((nmod + 255) / 256), dim3(256), 0, stream>>>(ad, send, mp);
  k_modB<<<dim3((BN * MM + 255) / 256), dim3(256), 0, stream>>>(send, sinit, mp);
  k_modC<<<dim3((BN * MM + 255) / 256, MODC), dim3(256), 0, stream>>>(ad, sinit, out, mp);
}